// Round 5
// baseline (450.338 us; speedup 1.0000x reference)
//
#include <hip/hip_runtime.h>
#include <hip/hip_bf16.h>

#define HDIM 1024
#define VOCAB 32000
#define TTOK 2048
#define BETAF 0.1f
#define NPAIRS 4

// fallback (128-tile) geometry
#define BM 128
#define BN 128
#define BK 64
#define MT (TTOK/BM)     // 16
#define NT (VOCAB/BN)    // 250
#define KSTEPS (HDIM/BK) // 16

// main (256-tile, 8-phase) geometry
#define BM2 256
#define MT2 (TTOK/BM2)   // 8
#define NT2 (VOCAB/BM2)  // 125
#define NWG2 (MT2*NT2*2) // 2000, %8==0

typedef __attribute__((ext_vector_type(4))) float f32x4;
typedef __attribute__((ext_vector_type(8))) short bf16x8;

__device__ __forceinline__ short f2bf(float f) {
    union { float f; unsigned u; } v; v.f = f;
    return (short)((v.u + 0x7FFFu + ((v.u >> 16) & 1u)) >> 16);  // RNE
}

__device__ __forceinline__ void gld_lds16(const void* g, void* l) {
    __builtin_amdgcn_global_load_lds(
        (const __attribute__((address_space(1))) unsigned int*)g,
        (__attribute__((address_space(3))) unsigned int*)l, 16, 0, 0);
}

// ---------------- fp32 -> bf16 pre-convert ---------------------------------
__global__ __launch_bounds__(256) void convert_kernel(
    const float* __restrict__ src, short* __restrict__ dst, int n8)
{
    int stride = gridDim.x * blockDim.x;
    for (int i = blockIdx.x * blockDim.x + threadIdx.x; i < n8; i += stride) {
        size_t off = (size_t)i * 8;
        f32x4 v0 = *(const f32x4*)(src + off);
        f32x4 v1 = *(const f32x4*)(src + off + 4);
        bf16x8 b;
        b[0]=f2bf(v0[0]); b[1]=f2bf(v0[1]); b[2]=f2bf(v0[2]); b[3]=f2bf(v0[3]);
        b[4]=f2bf(v1[0]); b[5]=f2bf(v1[1]); b[6]=f2bf(v1[2]); b[7]=f2bf(v1[3]);
        *(bf16x8*)(dst + off) = b;
    }
}

// ---------------- 256x256 8-phase GEMM helpers -----------------------------
// Stage one K-tile (A 256x64 + B 256x64 bf16) via 8 gld_lds/thread.
// Linear LDS dest; global source pre-swizzled kseg ^= row&7 (rule #21).
__device__ __forceinline__ void stage_tile(
    const short* __restrict__ Ag, const short* __restrict__ Bg, int kb,
    short* Al, short* Bl, int tid)
{
    const int r0   = tid >> 3;                 // 0..63
    const int ksg  = (tid & 7) ^ (r0 & 7);     // swizzled k-segment
    const int ldsb = (tid >> 6) << 10;         // wave-uniform base (w*1024 B)
    #pragma unroll
    for (int it = 0; it < 4; ++it) {
        int row = it * 64 + r0;
        size_t goff = (size_t)row * HDIM + kb + ksg * 8;
        int lb = it * 8192 + ldsb;
        gld_lds16(Ag + goff, (char*)Al + lb);
        gld_lds16(Bg + goff, (char*)Bl + lb);
    }
}

// Consume one staged K-tile: 4 phases x {ds_read, setprio, 16 MFMA, barrier}.
__device__ __forceinline__ void ktile(
    const short* __restrict__ Ab, const short* __restrict__ Bb,
    int arow0, int brow0, int lhi, f32x4 (&acc)[8][4])
{
    bf16x8 bq[2][4];
    #pragma unroll
    for (int kk = 0; kk < 2; ++kk)
        #pragma unroll
        for (int n = 0; n < 4; ++n) {
            int row = brow0 + n * 16;
            int byte = (row*128 + kk*64 + lhi*16) ^ ((row & 7) << 4);
            bq[kk][n] = *(const bf16x8*)((const char*)Bb + byte);
        }
    #pragma unroll
    for (int q = 0; q < 4; ++q) {
        bf16x8 af[2][2];
        #pragma unroll
        for (int kk = 0; kk < 2; ++kk)
            #pragma unroll
            for (int mm = 0; mm < 2; ++mm) {
                int row = arow0 + (q*2 + mm) * 16;
                int byte = (row*128 + kk*64 + lhi*16) ^ ((row & 7) << 4);
                af[kk][mm] = *(const bf16x8*)((const char*)Ab + byte);
            }
        __builtin_amdgcn_s_setprio(1);
        #pragma unroll
        for (int kk = 0; kk < 2; ++kk)
            #pragma unroll
            for (int mm = 0; mm < 2; ++mm)
                #pragma unroll
                for (int n = 0; n < 4; ++n)
                    acc[q*2+mm][n] = __builtin_amdgcn_mfma_f32_16x16x32_bf16(
                        af[kk][mm], bq[kk][n], acc[q*2+mm][n], 0, 0, 0);
        __builtin_amdgcn_s_setprio(0);
        __builtin_amdgcn_s_barrier();
    }
}

// partial layout (main path): [2][NT2][TTOK]
// NOTE: __launch_bounds__(512) ONLY — block must fit (8 waves, 2/SIMD) so the
// compiler caps VGPR at 256. Requesting min-2-waves/EU (round 4) capped VGPR
// at 128 and spilled ~80 regs in the K-loop (WRITE_SIZE 4->26 MB).
__global__ __launch_bounds__(512) void gemm_expsum_256(
    const short* __restrict__ Xb, const short* __restrict__ Wb,
    const float* __restrict__ B0, const float* __restrict__ B1,
    float* __restrict__ partial)
{
    __shared__ short As[2][BM2*BK];   // 64 KB
    __shared__ short Bs[2][BM2*BK];   // 64 KB
    __shared__ float red[4][BM2];     // 4 KB

    // bijective XCD swizzle (2000 % 8 == 0), tm fastest for W-panel L2 reuse
    int raw = blockIdx.x;
    int swz = (raw & 7) * (NWG2 / 8) + (raw >> 3);
    const int model = swz / (MT2 * NT2);
    int rem = swz % (MT2 * NT2);
    const int tn = rem / MT2;
    const int tm = rem % MT2;

    const short* __restrict__ X = Xb + (size_t)model * TTOK * HDIM;
    const short* __restrict__ W = Wb + (size_t)model * VOCAB * HDIM;
    const float* __restrict__ Bi = model ? B1 : B0;

    const int tid  = threadIdx.x;
    const int lane = tid & 63;
    const int w    = tid >> 6;
    const int wrM  = w >> 2, wn = w & 3;   // 2x4 wave grid; 128x64 out each
    const int l16  = lane & 15, lhi = lane >> 4;
    const int arow0 = wrM*128 + l16;
    const int brow0 = wn*64 + l16;

    const short* Ag = X + (size_t)tm * BM2 * HDIM;
    const short* Bg = W + (size_t)tn * BM2 * HDIM;

    f32x4 acc[8][4];
    #pragma unroll
    for (int m = 0; m < 8; ++m)
        #pragma unroll
        for (int n = 0; n < 4; ++n)
            acc[m][n] = (f32x4)0.f;

    // prologue: stage tiles 0,1; gate tile 0 (8 newest = tile 1 stay in flight)
    stage_tile(Ag, Bg, 0,  As[0], Bs[0], tid);
    stage_tile(Ag, Bg, BK, As[1], Bs[1], tid);
    asm volatile("s_waitcnt vmcnt(8)" ::: "memory");
    __builtin_amdgcn_s_barrier();
    __builtin_amdgcn_sched_barrier(0);

    #pragma unroll 1
    for (int t2 = 0; t2 < 8; ++t2) {
        // even tile 2*t2 in buf0
        ktile(As[0], Bs[0], arow0, brow0, lhi, acc);
        if (t2 < 7) {   // stage tile 2*t2+2 -> buf0 (all waves past ktile's final barrier)
            __builtin_amdgcn_sched_barrier(0);
            stage_tile(Ag, Bg, (2*t2 + 2) * BK, As[0], Bs[0], tid);
            asm volatile("s_waitcnt vmcnt(8)" ::: "memory");   // tile 2*t2+1 ready
        } else {
            asm volatile("s_waitcnt vmcnt(0)" ::: "memory");   // tile 15 ready
        }
        __builtin_amdgcn_s_barrier();
        __builtin_amdgcn_sched_barrier(0);
        // odd tile 2*t2+1 in buf1
        ktile(As[1], Bs[1], arow0, brow0, lhi, acc);
        if (t2 < 7) {
            __builtin_amdgcn_sched_barrier(0);
            stage_tile(Ag, Bg, (2*t2 + 3) * BK, As[1], Bs[1], tid);
            asm volatile("s_waitcnt vmcnt(8)" ::: "memory");   // tile 2*t2+2 ready
            __builtin_amdgcn_s_barrier();
            __builtin_amdgcn_sched_barrier(0);
        }
    }

    // epilogue: per-token sum of exp(logit + bias) over this block's 256 cols
    float bv[4];
    #pragma unroll
    for (int n = 0; n < 4; ++n)
        bv[n] = Bi[tn*BM2 + wn*64 + n*16 + l16];

    #pragma unroll
    for (int m = 0; m < 8; ++m) {
        #pragma unroll
        for (int j = 0; j < 4; ++j) {
            float s = 0.f;
            #pragma unroll
            for (int n = 0; n < 4; ++n)
                s += __expf(acc[m][n][j] + bv[n]);
            s += __shfl_xor(s, 1);
            s += __shfl_xor(s, 2);
            s += __shfl_xor(s, 4);
            s += __shfl_xor(s, 8);
            if (l16 == 0)
                red[wn][wrM*128 + m*16 + lhi*4 + j] = s;
        }
    }
    __syncthreads();
    if (tid < BM2) {
        float s = red[0][tid] + red[1][tid] + red[2][tid] + red[3][tid];
        partial[((size_t)model*NT2 + tn)*TTOK + tm*BM2 + tid] = s;
    }
}

// ---------------- fallback GEMM (inline convert, explicit swizzle) ---------
__global__ __launch_bounds__(256) void gemm_expsum_f32(
    const float* __restrict__ X0, const float* __restrict__ W0, const float* __restrict__ B0,
    const float* __restrict__ X1, const float* __restrict__ W1, const float* __restrict__ B1,
    float* __restrict__ partial)
{
    const int model = blockIdx.z;
    const float* __restrict__ X = model ? X1 : X0;
    const float* __restrict__ W = model ? W1 : W0;
    const float* __restrict__ Bi = model ? B1 : B0;
    const int tm = blockIdx.x;
    const int tn = blockIdx.y;

    __shared__ short As[BM*BK];
    __shared__ short Bs[BN*BK];
    __shared__ float red[2][BM];

    const int tid  = threadIdx.x;
    const int lane = tid & 63;
    const int w    = tid >> 6;
    const int wr   = w >> 1, wc = w & 1;
    const int l16  = lane & 15, lhi = lane >> 4;

    f32x4 acc[4][4];
    #pragma unroll
    for (int m = 0; m < 4; ++m)
        #pragma unroll
        for (int n = 0; n < 4; ++n)
            acc[m][n] = (f32x4)0.f;

    for (int ks = 0; ks < KSTEPS; ++ks) {
        __syncthreads();
        const int kbase = ks * BK;
        #pragma unroll
        for (int it = 0; it < 4; ++it) {
            int s = tid + it * 256;
            int row = s >> 3, kseg = s & 7;
            const float* g = X + (size_t)(tm*BM + row)*HDIM + kbase + kseg*8;
            f32x4 v0 = *(const f32x4*)g;
            f32x4 v1 = *(const f32x4*)(g + 4);
            bf16x8 b;
            b[0]=f2bf(v0[0]); b[1]=f2bf(v0[1]); b[2]=f2bf(v0[2]); b[3]=f2bf(v0[3]);
            b[4]=f2bf(v1[0]); b[5]=f2bf(v1[1]); b[6]=f2bf(v1[2]); b[7]=f2bf(v1[3]);
            int byte = (row*128 + kseg*16) ^ ((row & 7) << 4);
            *(bf16x8*)((char*)As + byte) = b;
        }
        #pragma unroll
        for (int it = 0; it < 4; ++it) {
            int s = tid + it * 256;
            int row = s >> 3, kseg = s & 7;
            const float* g = W + (size_t)(tn*BN + row)*HDIM + kbase + kseg*8;
            f32x4 v0 = *(const f32x4*)g;
            f32x4 v1 = *(const f32x4*)(g + 4);
            bf16x8 b;
            b[0]=f2bf(v0[0]); b[1]=f2bf(v0[1]); b[2]=f2bf(v0[2]); b[3]=f2bf(v0[3]);
            b[4]=f2bf(v1[0]); b[5]=f2bf(v1[1]); b[6]=f2bf(v1[2]); b[7]=f2bf(v1[3]);
            int byte = (row*128 + kseg*16) ^ ((row & 7) << 4);
            *(bf16x8*)((char*)Bs + byte) = b;
        }
        __syncthreads();

        bf16x8 af[2][4], bfr[2][4];
        #pragma unroll
        for (int kk = 0; kk < 2; ++kk) {
            #pragma unroll
            for (int m = 0; m < 4; ++m) {
                int row = wr*64 + m*16 + l16;
                int byte = (row*128 + kk*64 + lhi*16) ^ ((row & 7) << 4);
                af[kk][m] = *(const bf16x8*)((const char*)As + byte);
            }
            #pragma unroll
            for (int n = 0; n < 4; ++n) {
                int row = wc*64 + n*16 + l16;
                int byte = (row*128 + kk*64 + lhi*16) ^ ((row & 7) << 4);
                bfr[kk][n] = *(const bf16x8*)((const char*)Bs + byte);
            }
        }
        #pragma unroll
        for (int kk = 0; kk < 2; ++kk)
            #pragma unroll
            for (int m = 0; m < 4; ++m)
                #pragma unroll
                for (int n = 0; n < 4; ++n)
                    acc[m][n] = __builtin_amdgcn_mfma_f32_16x16x32_bf16(
                        af[kk][m], bfr[kk][n], acc[m][n], 0, 0, 0);
    }

    float bv[4];
    #pragma unroll
    for (int n = 0; n < 4; ++n)
        bv[n] = Bi[tn*BN + wc*64 + n*16 + l16];

    #pragma unroll
    for (int m = 0; m < 4; ++m) {
        #pragma unroll
        for (int j = 0; j < 4; ++j) {
            float s = 0.f;
            #pragma unroll
            for (int n = 0; n < 4; ++n)
                s += __expf(acc[m][n][j] + bv[n]);
            s += __shfl_xor(s, 1);
            s += __shfl_xor(s, 2);
            s += __shfl_xor(s, 4);
            s += __shfl_xor(s, 8);
            if (l16 == 0)
                red[wc][wr*64 + m*16 + lhi*4 + j] = s;
        }
    }
    __syncthreads();
    if (tid < BM) {
        float s = red[0][tid] + red[1][tid];
        partial[((size_t)model*NT + tn)*TTOK + tm*BM + tid] = s;
    }
}

// ---------------- exact fp32 target logits ---------------------------------
__global__ __launch_bounds__(256) void tgt_kernel(
    const float* __restrict__ X0, const float* __restrict__ W0, const float* __restrict__ B0,
    const float* __restrict__ X1, const float* __restrict__ W1, const float* __restrict__ B1,
    const int* __restrict__ target, float* __restrict__ tgt)
{
    int gw = blockIdx.x * 4 + (threadIdx.x >> 6);
    int lane = threadIdx.x & 63;
    int model = gw >> 11;
    int t = gw & (TTOK - 1);
    const float* X = model ? X1 : X0;
    const float* W = model ? W1 : W0;
    const float* Bi = model ? B1 : B0;
    int tg = target[t];
    int stg = tg < 0 ? 0 : (tg >= VOCAB ? VOCAB - 1 : tg);
    const float* xr = X + (size_t)t * HDIM;
    const float* wrow = W + (size_t)stg * HDIM;
    float s = 0.f;
    #pragma unroll
    for (int i = 0; i < 4; ++i) {
        int k = i * 256 + lane * 4;
        f32x4 xv = *(const f32x4*)(xr + k);
        f32x4 wv = *(const f32x4*)(wrow + k);
        s += xv[0]*wv[0] + xv[1]*wv[1] + xv[2]*wv[2] + xv[3]*wv[3];
    }
    s += __shfl_xor(s, 1);  s += __shfl_xor(s, 2);  s += __shfl_xor(s, 4);
    s += __shfl_xor(s, 8);  s += __shfl_xor(s, 16); s += __shfl_xor(s, 32);
    if (lane == 0)
        tgt[model * TTOK + t] = s + Bi[stg];
}

// ---------------- coalesced logZ reduction (nt = #vocab tiles) -------------
__global__ __launch_bounds__(256) void logz_kernel(
    const float* __restrict__ partial, const float* __restrict__ tgt,
    const int* __restrict__ target, float* __restrict__ tok_lp, int nt)
{
    int g = blockIdx.x * 256 + threadIdx.x;   // 0..4095
    int m = g >> 11;
    int t = g & (TTOK - 1);
    const float* p = partial + (size_t)m * nt * TTOK + t;
    float S = 0.f;
    for (int j = 0; j < nt; ++j) S += p[(size_t)j * TTOK];
    float lp = tgt[g] - __logf(S);
    if (target[t] == -100) lp = 0.f;
    tok_lp[g] = lp;
}

// ---------------- per-seq sums + DPO loss ----------------------------------
__global__ __launch_bounds__(512) void loss_kernel(
    const float* __restrict__ tok_lp, float* __restrict__ out)
{
    int tid = threadIdx.x;
    float acc = 0.f;
    #pragma unroll
    for (int i = 0; i < 8; ++i)
        acc += tok_lp[tid * 8 + i];
    acc += __shfl_xor(acc, 1);  acc += __shfl_xor(acc, 2);
    acc += __shfl_xor(acc, 4);  acc += __shfl_xor(acc, 8);
    acc += __shfl_xor(acc, 16);
    __shared__ float ps[16];
    if ((tid & 31) == 0) ps[tid >> 5] = acc;
    __syncthreads();
    if (tid == 0) {
        float loss = 0.f;
        #pragma unroll
        for (int p = 0; p < NPAIRS; ++p) {
            float cho = ps[2*p]     - ps[8 + 2*p];
            float rej = ps[2*p + 1] - ps[8 + 2*p + 1];
            float z = BETAF * (cho - rej);
            float lsig = fminf(z, 0.f) - log1pf(__expf(-fabsf(z)));
            loss += -lsig;
        }
        out[0] = loss / (float)NPAIRS;
    }
}

// fallback finalize: single block, NT=250 layout
__global__ __launch_bounds__(512) void finalize_kernel(
    const float* __restrict__ partial, const float* __restrict__ tgt,
    const int* __restrict__ target, float* __restrict__ out)
{
    int tid = threadIdx.x;
    float acc = 0.f;
    #pragma unroll
    for (int i = 0; i < 8; ++i) {
        int g = tid * 8 + i;
        int model = g >> 11;
        int t = g & (TTOK - 1);
        const float* p = partial + (size_t)model * NT * TTOK + t;
        float S = 0.f;
        for (int j = 0; j < NT; ++j) S += p[(size_t)j * TTOK];
        float lp = tgt[g] - __logf(S);
        if (target[t] == -100) lp = 0.f;
        acc += lp;
    }
    acc += __shfl_xor(acc, 1);  acc += __shfl_xor(acc, 2);
    acc += __shfl_xor(acc, 4);  acc += __shfl_xor(acc, 8);
    acc += __shfl_xor(acc, 16);
    __shared__ float ps[16];
    if ((tid & 31) == 0) ps[tid >> 5] = acc;
    __syncthreads();
    if (tid == 0) {
        float loss = 0.f;
        #pragma unroll
        for (int p = 0; p < NPAIRS; ++p) {
            float cho = ps[2*p]     - ps[8 + 2*p];
            float rej = ps[2*p + 1] - ps[8 + 2*p + 1];
            float z = BETAF * (cho - rej);
            float lsig = fminf(z, 0.f) - log1pf(__expf(-fabsf(z)));
            loss += -lsig;
        }
        out[0] = loss / (float)NPAIRS;
    }
}

extern "C" void kernel_launch(void* const* d_in, const int* in_sizes, int n_in,
                              void* d_out, int out_size, void* d_ws, size_t ws_size,
                              hipStream_t stream) {
    const float* x    = (const float*)d_in[0];
    const float* wgt  = (const float*)d_in[1];
    const float* bias = (const float*)d_in[2];
    const float* rx   = (const float*)d_in[3];
    const float* rwgt = (const float*)d_in[4];
    const float* rb   = (const float*)d_in[5];
    const int* target = (const int*)d_in[6];
    float* out = (float*)d_out;

    // ws layout (partial region sized for the larger NT=250 fallback layout)
    float* partial = (float*)d_ws;                       // up to 2*250*2048 f = 4 MB
    float* tgtb    = partial + (size_t)2 * NT * TTOK;    // 4096 f
    float* tok_lp  = tgtb + 2 * TTOK;                    // 4096 f
    short* Xb      = (short*)(tok_lp + 2 * TTOK);        // 8 MB
    short* Wb      = Xb + (size_t)2 * TTOK * HDIM;       // 131 MB
    size_t need = (size_t)((char*)(Wb + (size_t)2 * VOCAB * HDIM) - (char*)d_ws);

    if (ws_size >= need) {
        int xn8 = TTOK * HDIM / 8;
        int wn8 = VOCAB * HDIM / 8;
        convert_kernel<<<1024, 256, 0, stream>>>(x,    Xb,                       xn8);
        convert_kernel<<<1024, 256, 0, stream>>>(rx,   Xb + (size_t)TTOK*HDIM,   xn8);
        convert_kernel<<<2048, 256, 0, stream>>>(wgt,  Wb,                       wn8);
        convert_kernel<<<2048, 256, 0, stream>>>(rwgt, Wb + (size_t)VOCAB*HDIM,  wn8);
        gemm_expsum_256<<<NWG2, 512, 0, stream>>>(Xb, Wb, bias, rb, partial);
        tgt_kernel<<<(2 * TTOK) / 4, 256, 0, stream>>>(x, wgt, bias, rx, rwgt, rb, target, tgtb);
        logz_kernel<<<16, 256, 0, stream>>>(partial, tgtb, target, tok_lp, NT2);
        loss_kernel<<<1, 512, 0, stream>>>(tok_lp, out);
    } else {
        dim3 grid(MT, NT, 2);
        gemm_expsum_f32<<<grid, 256, 0, stream>>>(x, wgt, bias, rx, rwgt, rb, partial);
        tgt_kernel<<<(2 * TTOK) / 4, 256, 0, stream>>>(x, wgt, bias, rx, rwgt, rb, target, tgtb);
        finalize_kernel<<<1, 512, 0, stream>>>(partial, tgtb, target, out);
    }
}

// Round 6
// 418.111 us; speedup vs baseline: 1.0771x; 1.0771x over previous
//
#include <hip/hip_runtime.h>
#include <hip/hip_bf16.h>

#define HDIM 1024
#define VOCAB 32000
#define TTOK 2048
#define BETAF 0.1f
#define NPAIRS 4

// fallback (128-tile) geometry
#define BM 128
#define BN 128
#define BK 64
#define MT (TTOK/BM)     // 16
#define NT (VOCAB/BN)    // 250
#define KSTEPS (HDIM/BK) // 16

// main (256-tile, phased) geometry
#define BM2 256
#define MT2 (TTOK/BM2)   // 8
#define NT2 (VOCAB/BM2)  // 125
#define NWG2 (MT2*NT2*2) // 2000, %8==0
#define KSTEPS2 (HDIM/BK) // 16

typedef __attribute__((ext_vector_type(4))) float f32x4;
typedef __attribute__((ext_vector_type(8))) short bf16x8;

__device__ __forceinline__ short f2bf(float f) {
    union { float f; unsigned u; } v; v.f = f;
    return (short)((v.u + 0x7FFFu + ((v.u >> 16) & 1u)) >> 16);  // RNE
}

__device__ __forceinline__ void gld_lds16(const void* g, void* l) {
    __builtin_amdgcn_global_load_lds(
        (const __attribute__((address_space(1))) unsigned int*)g,
        (__attribute__((address_space(3))) unsigned int*)l, 16, 0, 0);
}

// ---------------- fp32 -> bf16 pre-convert ---------------------------------
__global__ __launch_bounds__(256) void convert_kernel(
    const float* __restrict__ src, short* __restrict__ dst, int n8)
{
    int stride = gridDim.x * blockDim.x;
    for (int i = blockIdx.x * blockDim.x + threadIdx.x; i < n8; i += stride) {
        size_t off = (size_t)i * 8;
        f32x4 v0 = *(const f32x4*)(src + off);
        f32x4 v1 = *(const f32x4*)(src + off + 4);
        bf16x8 b;
        b[0]=f2bf(v0[0]); b[1]=f2bf(v0[1]); b[2]=f2bf(v0[2]); b[3]=f2bf(v0[3]);
        b[4]=f2bf(v1[0]); b[5]=f2bf(v1[1]); b[6]=f2bf(v1[2]); b[7]=f2bf(v1[3]);
        *(bf16x8*)(dst + off) = b;
    }
}

// Stage one 64-row quarter (`it`) of a 256x64 bf16 tile (A or B) via 1 gld/thread.
// Linear LDS dest; global source pre-swizzled kseg ^= row&7 (rule #21).
__device__ __forceinline__ void stage_one(
    const short* __restrict__ base, int kb, int it, void* ldsTile, int tid)
{
    int r0  = tid >> 3;                 // 0..63
    int ksg = (tid & 7) ^ (r0 & 7);     // swizzled k-segment
    int row = it * 64 + r0;
    gld_lds16(base + (size_t)row * HDIM + kb + ksg * 8,
              (char*)ldsTile + it * 8192 + ((tid >> 6) << 10));
}

// ---------------- 256x256 phased GEMM (m201-shaped) ------------------------
// partial layout (main path): [2][NT2][TTOK]
__global__ __launch_bounds__(512) void gemm_expsum_256(
    const short* __restrict__ Xb, const short* __restrict__ Wb,
    const float* __restrict__ B0, const float* __restrict__ B1,
    float* __restrict__ partial)
{
    __shared__ short As[2][BM2*BK];   // 64 KB
    __shared__ short Bs[2][BM2*BK];   // 64 KB
    __shared__ float red[4][BM2];     // 4 KB

    // bijective XCD swizzle (2000 % 8 == 0), tm fastest for W-panel L2 reuse
    int raw = blockIdx.x;
    int swz = (raw & 7) * (NWG2 / 8) + (raw >> 3);
    const int model = swz / (MT2 * NT2);
    int rem = swz % (MT2 * NT2);
    const int tn = rem / MT2;
    const int tm = rem % MT2;

    const short* __restrict__ X = Xb + (size_t)model * TTOK * HDIM;
    const short* __restrict__ W = Wb + (size_t)model * VOCAB * HDIM;
    const float* __restrict__ Bi = model ? B1 : B0;

    const int tid  = threadIdx.x;
    const int lane = tid & 63;
    const int w    = tid >> 6;
    const int wrM  = w >> 2, wn = w & 3;   // 2x4 wave grid; 128x64 out each
    const int l16  = lane & 15, lhi = lane >> 4;
    const int arow0 = wrM*128 + l16;
    const int brow0 = wn*64 + l16;

    const short* Ag = X + (size_t)tm * BM2 * HDIM;
    const short* Bg = W + (size_t)tn * BM2 * HDIM;

    f32x4 acc[8][4];
    #pragma unroll
    for (int m = 0; m < 8; ++m)
        #pragma unroll
        for (int n = 0; n < 4; ++n)
            acc[m][n] = (f32x4)0.f;

    // prologue: stage tiles 0,1 (16 gld/thread); gate tile 0 (tile 1's 8 stay in flight)
    #pragma unroll
    for (int it = 0; it < 4; ++it) {
        stage_one(Ag, 0, it, As[0], tid);
        stage_one(Bg, 0, it, Bs[0], tid);
    }
    #pragma unroll
    for (int it = 0; it < 4; ++it) {
        stage_one(Ag, BK, it, As[1], tid);
        stage_one(Bg, BK, it, Bs[1], tid);
    }
    asm volatile("s_waitcnt vmcnt(8)" ::: "memory");
    __builtin_amdgcn_s_barrier();

    #pragma unroll 1
    for (int t2 = 0; t2 < KSTEPS2; ++t2) {
        const int cur = t2 & 1;
        const short* Ab = As[cur];
        const short* Bb = Bs[cur];
        const int kb2 = (t2 + 2) * BK;
        const bool st = (t2 < KSTEPS2 - 2);   // stage tile t2+2 this iter?

        bf16x8 bq[2][4];   // B fragments for whole tile, read at phase 0

        // 4 phases; phase q = output quadrant q (rows arow0 + q*32..+32), K=64.
        // Staging of tile t2+2 goes into buf[cur] (same buffer) — each quarter
        // is staged only in a phase AFTER all its readers' lgkmcnt(0)+barrier:
        //   B quarters: all consumed in phase 0  -> staged in phases 1,2
        //   A q0/q2 (rows 0-63,128-191): consumed phases 0,1 -> staged phase 3
        //   A q1/q3 (rows 64-127,192-255): consumed phases 2,3 -> staged inter-tile
        #pragma unroll
        for (int q = 0; q < 4; ++q) {
            bf16x8 af[2][2];
            #pragma unroll
            for (int kk = 0; kk < 2; ++kk)
                #pragma unroll
                for (int mm = 0; mm < 2; ++mm) {
                    int row = arow0 + q*32 + mm*16;
                    int byte = (row*128 + kk*64 + lhi*16) ^ ((row & 7) << 4);
                    af[kk][mm] = *(const bf16x8*)((const char*)Ab + byte);
                }
            if (q == 0) {
                #pragma unroll
                for (int kk = 0; kk < 2; ++kk)
                    #pragma unroll
                    for (int n = 0; n < 4; ++n) {
                        int row = brow0 + n * 16;
                        int byte = (row*128 + kk*64 + lhi*16) ^ ((row & 7) << 4);
                        bq[kk][n] = *(const bf16x8*)((const char*)Bb + byte);
                    }
            }
            if (st) {
                if (q == 1) {
                    stage_one(Bg, kb2, 0, Bs[cur], tid);
                    stage_one(Bg, kb2, 1, Bs[cur], tid);
                } else if (q == 2) {
                    stage_one(Bg, kb2, 2, Bs[cur], tid);
                    stage_one(Bg, kb2, 3, Bs[cur], tid);
                } else if (q == 3) {
                    stage_one(Ag, kb2, 0, As[cur], tid);
                    stage_one(Ag, kb2, 2, As[cur], tid);
                }
            }
            __builtin_amdgcn_s_barrier();
            asm volatile("s_waitcnt lgkmcnt(0)" ::: "memory");
            __builtin_amdgcn_s_setprio(1);
            #pragma unroll
            for (int kk = 0; kk < 2; ++kk)
                #pragma unroll
                for (int mm = 0; mm < 2; ++mm)
                    #pragma unroll
                    for (int n = 0; n < 4; ++n)
                        acc[q*2+mm][n] = __builtin_amdgcn_mfma_f32_16x16x32_bf16(
                            af[kk][mm], bq[kk][n], acc[q*2+mm][n], 0, 0, 0);
            __builtin_amdgcn_s_setprio(0);
            __builtin_amdgcn_s_barrier();
        }

        if (st) {
            stage_one(Ag, kb2, 1, As[cur], tid);
            stage_one(Ag, kb2, 3, As[cur], tid);
            asm volatile("s_waitcnt vmcnt(8)" ::: "memory");   // tile t2+1 landed
            __builtin_amdgcn_s_barrier();
        } else if (t2 == KSTEPS2 - 2) {
            asm volatile("s_waitcnt vmcnt(0)" ::: "memory");   // tile 15 landed
            __builtin_amdgcn_s_barrier();
        }
    }

    // epilogue: per-token sum of exp(logit + bias) over this block's 256 cols
    float bv[4];
    #pragma unroll
    for (int n = 0; n < 4; ++n)
        bv[n] = Bi[tn*BM2 + wn*64 + n*16 + l16];

    #pragma unroll
    for (int m = 0; m < 8; ++m) {
        #pragma unroll
        for (int j = 0; j < 4; ++j) {
            float s = 0.f;
            #pragma unroll
            for (int n = 0; n < 4; ++n)
                s += __expf(acc[m][n][j] + bv[n]);
            s += __shfl_xor(s, 1);
            s += __shfl_xor(s, 2);
            s += __shfl_xor(s, 4);
            s += __shfl_xor(s, 8);
            if (l16 == 0)
                red[wn][wrM*128 + m*16 + lhi*4 + j] = s;
        }
    }
    __syncthreads();
    if (tid < BM2) {
        float s = red[0][tid] + red[1][tid] + red[2][tid] + red[3][tid];
        partial[((size_t)model*NT2 + tn)*TTOK + tm*BM2 + tid] = s;
    }
}

// ---------------- fallback GEMM (inline convert, explicit swizzle) ---------
__global__ __launch_bounds__(256) void gemm_expsum_f32(
    const float* __restrict__ X0, const float* __restrict__ W0, const float* __restrict__ B0,
    const float* __restrict__ X1, const float* __restrict__ W1, const float* __restrict__ B1,
    float* __restrict__ partial)
{
    const int model = blockIdx.z;
    const float* __restrict__ X = model ? X1 : X0;
    const float* __restrict__ W = model ? W1 : W0;
    const float* __restrict__ Bi = model ? B1 : B0;
    const int tm = blockIdx.x;
    const int tn = blockIdx.y;

    __shared__ short As[BM*BK];
    __shared__ short Bs[BN*BK];
    __shared__ float red[2][BM];

    const int tid  = threadIdx.x;
    const int lane = tid & 63;
    const int w    = tid >> 6;
    const int wr   = w >> 1, wc = w & 1;
    const int l16  = lane & 15, lhi = lane >> 4;

    f32x4 acc[4][4];
    #pragma unroll
    for (int m = 0; m < 4; ++m)
        #pragma unroll
        for (int n = 0; n < 4; ++n)
            acc[m][n] = (f32x4)0.f;

    for (int ks = 0; ks < KSTEPS; ++ks) {
        __syncthreads();
        const int kbase = ks * BK;
        #pragma unroll
        for (int it = 0; it < 4; ++it) {
            int s = tid + it * 256;
            int row = s >> 3, kseg = s & 7;
            const float* g = X + (size_t)(tm*BM + row)*HDIM + kbase + kseg*8;
            f32x4 v0 = *(const f32x4*)g;
            f32x4 v1 = *(const f32x4*)(g + 4);
            bf16x8 b;
            b[0]=f2bf(v0[0]); b[1]=f2bf(v0[1]); b[2]=f2bf(v0[2]); b[3]=f2bf(v0[3]);
            b[4]=f2bf(v1[0]); b[5]=f2bf(v1[1]); b[6]=f2bf(v1[2]); b[7]=f2bf(v1[3]);
            int byte = (row*128 + kseg*16) ^ ((row & 7) << 4);
            *(bf16x8*)((char*)As + byte) = b;
        }
        #pragma unroll
        for (int it = 0; it < 4; ++it) {
            int s = tid + it * 256;
            int row = s >> 3, kseg = s & 7;
            const float* g = W + (size_t)(tn*BN + row)*HDIM + kbase + kseg*8;
            f32x4 v0 = *(const f32x4*)g;
            f32x4 v1 = *(const f32x4*)(g + 4);
            bf16x8 b;
            b[0]=f2bf(v0[0]); b[1]=f2bf(v0[1]); b[2]=f2bf(v0[2]); b[3]=f2bf(v0[3]);
            b[4]=f2bf(v1[0]); b[5]=f2bf(v1[1]); b[6]=f2bf(v1[2]); b[7]=f2bf(v1[3]);
            int byte = (row*128 + kseg*16) ^ ((row & 7) << 4);
            *(bf16x8*)((char*)Bs + byte) = b;
        }
        __syncthreads();

        bf16x8 af[2][4], bfr[2][4];
        #pragma unroll
        for (int kk = 0; kk < 2; ++kk) {
            #pragma unroll
            for (int m = 0; m < 4; ++m) {
                int row = wr*64 + m*16 + l16;
                int byte = (row*128 + kk*64 + lhi*16) ^ ((row & 7) << 4);
                af[kk][m] = *(const bf16x8*)((const char*)As + byte);
            }
            #pragma unroll
            for (int n = 0; n < 4; ++n) {
                int row = wc*64 + n*16 + l16;
                int byte = (row*128 + kk*64 + lhi*16) ^ ((row & 7) << 4);
                bfr[kk][n] = *(const bf16x8*)((const char*)Bs + byte);
            }
        }
        #pragma unroll
        for (int kk = 0; kk < 2; ++kk)
            #pragma unroll
            for (int m = 0; m < 4; ++m)
                #pragma unroll
                for (int n = 0; n < 4; ++n)
                    acc[m][n] = __builtin_amdgcn_mfma_f32_16x16x32_bf16(
                        af[kk][m], bfr[kk][n], acc[m][n], 0, 0, 0);
    }

    float bv[4];
    #pragma unroll
    for (int n = 0; n < 4; ++n)
        bv[n] = Bi[tn*BN + wc*64 + n*16 + l16];

    #pragma unroll
    for (int m = 0; m < 4; ++m) {
        #pragma unroll
        for (int j = 0; j < 4; ++j) {
            float s = 0.f;
            #pragma unroll
            for (int n = 0; n < 4; ++n)
                s += __expf(acc[m][n][j] + bv[n]);
            s += __shfl_xor(s, 1);
            s += __shfl_xor(s, 2);
            s += __shfl_xor(s, 4);
            s += __shfl_xor(s, 8);
            if (l16 == 0)
                red[wc][wr*64 + m*16 + lhi*4 + j] = s;
        }
    }
    __syncthreads();
    if (tid < BM) {
        float s = red[0][tid] + red[1][tid];
        partial[((size_t)model*NT + tn)*TTOK + tm*BM + tid] = s;
    }
}

// ---------------- exact fp32 target logits ---------------------------------
__global__ __launch_bounds__(256) void tgt_kernel(
    const float* __restrict__ X0, const float* __restrict__ W0, const float* __restrict__ B0,
    const float* __restrict__ X1, const float* __restrict__ W1, const float* __restrict__ B1,
    const int* __restrict__ target, float* __restrict__ tgt)
{
    int gw = blockIdx.x * 4 + (threadIdx.x >> 6);
    int lane = threadIdx.x & 63;
    int model = gw >> 11;
    int t = gw & (TTOK - 1);
    const float* X = model ? X1 : X0;
    const float* W = model ? W1 : W0;
    const float* Bi = model ? B1 : B0;
    int tg = target[t];
    int stg = tg < 0 ? 0 : (tg >= VOCAB ? VOCAB - 1 : tg);
    const float* xr = X + (size_t)t * HDIM;
    const float* wrow = W + (size_t)stg * HDIM;
    float s = 0.f;
    #pragma unroll
    for (int i = 0; i < 4; ++i) {
        int k = i * 256 + lane * 4;
        f32x4 xv = *(const f32x4*)(xr + k);
        f32x4 wv = *(const f32x4*)(wrow + k);
        s += xv[0]*wv[0] + xv[1]*wv[1] + xv[2]*wv[2] + xv[3]*wv[3];
    }
    s += __shfl_xor(s, 1);  s += __shfl_xor(s, 2);  s += __shfl_xor(s, 4);
    s += __shfl_xor(s, 8);  s += __shfl_xor(s, 16); s += __shfl_xor(s, 32);
    if (lane == 0)
        tgt[model * TTOK + t] = s + Bi[stg];
}

// ---------------- coalesced logZ reduction (nt = #vocab tiles) -------------
__global__ __launch_bounds__(256) void logz_kernel(
    const float* __restrict__ partial, const float* __restrict__ tgt,
    const int* __restrict__ target, float* __restrict__ tok_lp, int nt)
{
    int g = blockIdx.x * 256 + threadIdx.x;   // 0..4095
    int m = g >> 11;
    int t = g & (TTOK - 1);
    const float* p = partial + (size_t)m * nt * TTOK + t;
    float S = 0.f;
    for (int j = 0; j < nt; ++j) S += p[(size_t)j * TTOK];
    float lp = tgt[g] - __logf(S);
    if (target[t] == -100) lp = 0.f;
    tok_lp[g] = lp;
}

// ---------------- per-seq sums + DPO loss ----------------------------------
__global__ __launch_bounds__(512) void loss_kernel(
    const float* __restrict__ tok_lp, float* __restrict__ out)
{
    int tid = threadIdx.x;
    float acc = 0.f;
    #pragma unroll
    for (int i = 0; i < 8; ++i)
        acc += tok_lp[tid * 8 + i];
    acc += __shfl_xor(acc, 1);  acc += __shfl_xor(acc, 2);
    acc += __shfl_xor(acc, 4);  acc += __shfl_xor(acc, 8);
    acc += __shfl_xor(acc, 16);
    __shared__ float ps[16];
    if ((tid & 31) == 0) ps[tid >> 5] = acc;
    __syncthreads();
    if (tid == 0) {
        float loss = 0.f;
        #pragma unroll
        for (int p = 0; p < NPAIRS; ++p) {
            float cho = ps[2*p]     - ps[8 + 2*p];
            float rej = ps[2*p + 1] - ps[8 + 2*p + 1];
            float z = BETAF * (cho - rej);
            float lsig = fminf(z, 0.f) - log1pf(__expf(-fabsf(z)));
            loss += -lsig;
        }
        out[0] = loss / (float)NPAIRS;
    }
}

// fallback finalize: single block, NT=250 layout
__global__ __launch_bounds__(512) void finalize_kernel(
    const float* __restrict__ partial, const float* __restrict__ tgt,
    const int* __restrict__ target, float* __restrict__ out)
{
    int tid = threadIdx.x;
    float acc = 0.f;
    #pragma unroll
    for (int i = 0; i < 8; ++i) {
        int g = tid * 8 + i;
        int model = g >> 11;
        int t = g & (TTOK - 1);
        const float* p = partial + (size_t)model * NT * TTOK + t;
        float S = 0.f;
        for (int j = 0; j < NT; ++j) S += p[(size_t)j * TTOK];
        float lp = tgt[g] - __logf(S);
        if (target[t] == -100) lp = 0.f;
        acc += lp;
    }
    acc += __shfl_xor(acc, 1);  acc += __shfl_xor(acc, 2);
    acc += __shfl_xor(acc, 4);  acc += __shfl_xor(acc, 8);
    acc += __shfl_xor(acc, 16);
    __shared__ float ps[16];
    if ((tid & 31) == 0) ps[tid >> 5] = acc;
    __syncthreads();
    if (tid == 0) {
        float loss = 0.f;
        #pragma unroll
        for (int p = 0; p < NPAIRS; ++p) {
            float cho = ps[2*p]     - ps[8 + 2*p];
            float rej = ps[2*p + 1] - ps[8 + 2*p + 1];
            float z = BETAF * (cho - rej);
            float lsig = fminf(z, 0.f) - log1pf(__expf(-fabsf(z)));
            loss += -lsig;
        }
        out[0] = loss / (float)NPAIRS;
    }
}

extern "C" void kernel_launch(void* const* d_in, const int* in_sizes, int n_in,
                              void* d_out, int out_size, void* d_ws, size_t ws_size,
                              hipStream_t stream) {
    const float* x    = (const float*)d_in[0];
    const float* wgt  = (const float*)d_in[1];
    const float* bias = (const float*)d_in[2];
    const float* rx   = (const float*)d_in[3];
    const float* rwgt = (const float*)d_in[4];
    const float* rb   = (const float*)d_in[5];
    const int* target = (const int*)d_in[6];
    float* out = (float*)d_out;

    // ws layout (partial region sized for the larger NT=250 fallback layout)
    float* partial = (float*)d_ws;                       // up to 2*250*2048 f = 4 MB
    float* tgtb    = partial + (size_t)2 * NT * TTOK;    // 4096 f
    float* tok_lp  = tgtb + 2 * TTOK;                    // 4096 f
    short* Xb      = (short*)(tok_lp + 2 * TTOK);        // 8 MB
    short* Wb      = Xb + (size_t)2 * TTOK * HDIM;       // 131 MB
    size_t need = (size_t)((char*)(Wb + (size_t)2 * VOCAB * HDIM) - (char*)d_ws);

    if (ws_size >= need) {
        int xn8 = TTOK * HDIM / 8;
        int wn8 = VOCAB * HDIM / 8;
        convert_kernel<<<1024, 256, 0, stream>>>(x,    Xb,                       xn8);
        convert_kernel<<<1024, 256, 0, stream>>>(rx,   Xb + (size_t)TTOK*HDIM,   xn8);
        convert_kernel<<<2048, 256, 0, stream>>>(wgt,  Wb,                       wn8);
        convert_kernel<<<2048, 256, 0, stream>>>(rwgt, Wb + (size_t)VOCAB*HDIM,  wn8);
        gemm_expsum_256<<<NWG2, 512, 0, stream>>>(Xb, Wb, bias, rb, partial);
        tgt_kernel<<<(2 * TTOK) / 4, 256, 0, stream>>>(x, wgt, bias, rx, rwgt, rb, target, tgtb);
        logz_kernel<<<16, 256, 0, stream>>>(partial, tgtb, target, tok_lp, NT2);
        loss_kernel<<<1, 512, 0, stream>>>(tok_lp, out);
    } else {
        dim3 grid(MT, NT, 2);
        gemm_expsum_f32<<<grid, 256, 0, stream>>>(x, wgt, bias, rx, rwgt, rb, partial);
        tgt_kernel<<<(2 * TTOK) / 4, 256, 0, stream>>>(x, wgt, bias, rx, rwgt, rb, target, tgtb);
        finalize_kernel<<<1, 512, 0, stream>>>(partial, tgtb, target, out);
    }
}

// Round 7
// 409.295 us; speedup vs baseline: 1.1003x; 1.0215x over previous
//
#include <hip/hip_runtime.h>
#include <hip/hip_bf16.h>

#define HDIM 1024
#define VOCAB 32000
#define TTOK 2048
#define BETAF 0.1f
#define NPAIRS 4

#define BM 128
#define BN 128
#define BK 64
#define MT (TTOK/BM)     // 16
#define NT (VOCAB/BN)    // 250
#define KSTEPS (HDIM/BK) // 16
#define NWG (MT*NT*2)    // 8000, %8==0

#define CONV_BLOCKS 2048
#define TGT_BLOCKS  1024   // 4 wave-tasks each -> 4096 (model,token) dots

typedef __attribute__((ext_vector_type(4))) float f32x4;
typedef __attribute__((ext_vector_type(8))) short bf16x8;

__device__ __forceinline__ short f2bf(float f) {
    union { float f; unsigned u; } v; v.f = f;
    return (short)((v.u + 0x7FFFu + ((v.u >> 16) & 1u)) >> 16);  // RNE
}

__device__ __forceinline__ void gld_lds16(const void* g, void* l) {
    __builtin_amdgcn_global_load_lds(
        (const __attribute__((address_space(1))) unsigned int*)g,
        (__attribute__((address_space(3))) unsigned int*)l, 16, 0, 0);
}

// ---------------- fused prep: fp32->bf16 converts + exact fp32 tgt logits --
// blocks [0, CONV_BLOCKS): grid-stride convert of {x, rx, wgt, rwgt}
// blocks [CONV_BLOCKS, CONV_BLOCKS+TGT_BLOCKS): tgt[model][t] = <X[t], W[target[t]]> + b
__global__ __launch_bounds__(256) void prep_kernel(
    const float* __restrict__ x,    const float* __restrict__ rx,
    const float* __restrict__ wgt,  const float* __restrict__ rwgt,
    const float* __restrict__ bias, const float* __restrict__ rb,
    short* __restrict__ Xb, short* __restrict__ Wb,
    const int* __restrict__ target, float* __restrict__ tgt)
{
    const int b = blockIdx.x;
    if (b < CONV_BLOCKS) {
        const int XN8 = TTOK * HDIM / 8;      // 262144
        const int WN8 = VOCAB * HDIM / 8;     // 4096000
        const int TOT = 2 * XN8 + 2 * WN8;    // 8716288
        const int stride = CONV_BLOCKS * 256;
        for (int i = b * 256 + threadIdx.x; i < TOT; i += stride) {
            const float* src; short* dst; int off;
            if (i < XN8)            { src = x;    dst = Xb;                          off = i; }
            else if (i < 2*XN8)     { src = rx;   dst = Xb + (size_t)TTOK*HDIM;      off = i - XN8; }
            else if (i < 2*XN8+WN8) { src = wgt;  dst = Wb;                          off = i - 2*XN8; }
            else                    { src = rwgt; dst = Wb + (size_t)VOCAB*HDIM;     off = i - 2*XN8 - WN8; }
            size_t e = (size_t)off * 8;
            f32x4 v0 = *(const f32x4*)(src + e);
            f32x4 v1 = *(const f32x4*)(src + e + 4);
            bf16x8 o;
            o[0]=f2bf(v0[0]); o[1]=f2bf(v0[1]); o[2]=f2bf(v0[2]); o[3]=f2bf(v0[3]);
            o[4]=f2bf(v1[0]); o[5]=f2bf(v1[1]); o[6]=f2bf(v1[2]); o[7]=f2bf(v1[3]);
            *(bf16x8*)(dst + e) = o;
        }
    } else {
        int gw = (b - CONV_BLOCKS) * 4 + (threadIdx.x >> 6);  // 0..4095
        int lane = threadIdx.x & 63;
        int model = gw >> 11;
        int t = gw & (TTOK - 1);
        const float* X  = model ? rx : x;
        const float* W  = model ? rwgt : wgt;
        const float* Bi = model ? rb : bias;
        int tg = target[t];
        int stg = tg < 0 ? 0 : (tg >= VOCAB ? VOCAB - 1 : tg);
        const float* xr = X + (size_t)t * HDIM;
        const float* wrow = W + (size_t)stg * HDIM;
        float s = 0.f;
        #pragma unroll
        for (int i = 0; i < 4; ++i) {
            int k = i * 256 + lane * 4;
            f32x4 xv = *(const f32x4*)(xr + k);
            f32x4 wv = *(const f32x4*)(wrow + k);
            s += xv[0]*wv[0] + xv[1]*wv[1] + xv[2]*wv[2] + xv[3]*wv[3];
        }
        s += __shfl_xor(s, 1);  s += __shfl_xor(s, 2);  s += __shfl_xor(s, 4);
        s += __shfl_xor(s, 8);  s += __shfl_xor(s, 16); s += __shfl_xor(s, 32);
        if (lane == 0)
            tgt[model * TTOK + t] = s + Bi[stg];
    }
}

// ---------------- main GEMM: round-3 kernel (933 TF, m97-structure ceiling) -
// Layout invariant (rule #21): LDS dest linear (gld_lds writes base+lane*16);
// global source pre-swizzled kseg^=(row&7); reads XOR the same involution.
__global__ __launch_bounds__(256, 4) void gemm_expsum_bf16(
    const short* __restrict__ Xb, const short* __restrict__ Wb,
    const float* __restrict__ B0, const float* __restrict__ B1,
    float* __restrict__ partial)
{
    // T1: bijective XCD swizzle (NWG % 8 == 0), tm fastest for W-panel reuse
    int raw = blockIdx.x;
    int swz = (raw & 7) * (NWG / 8) + (raw >> 3);
    const int model = swz / (MT * NT);
    int rem = swz % (MT * NT);
    const int tn = rem / MT;
    const int tm = rem % MT;

    const short* __restrict__ X = Xb + (size_t)model * TTOK * HDIM;
    const short* __restrict__ W = Wb + (size_t)model * VOCAB * HDIM;
    const float* __restrict__ Bi = model ? B1 : B0;

    __shared__ short As[BM*BK];   // 16 KB
    __shared__ short Bs[BN*BK];   // 16 KB
    __shared__ float red[2][BM];

    const int tid  = threadIdx.x;
    const int lane = tid & 63;
    const int w    = tid >> 6;
    const int wr   = w >> 1, wc = w & 1;    // 2x2 waves, 64x64 out each
    const int l16  = lane & 15, lhi = lane >> 4;

    f32x4 acc[4][4];
    #pragma unroll
    for (int m = 0; m < 4; ++m)
        #pragma unroll
        for (int n = 0; n < 4; ++n)
            acc[m][n] = (f32x4)0.f;

    const short* Abase = X + (size_t)tm * BM * HDIM;
    const short* Bbase = W + (size_t)tn * BN * HDIM;

    for (int ks = 0; ks < KSTEPS; ++ks) {
        const int kbase = ks * BK;
        // stage: 1024 x 16B chunks per tile. Linear LDS slot c holds global
        // chunk (row = c>>3, kseg = (c&7) ^ (row&7)).
        #pragma unroll
        for (int it = 0; it < 4; ++it) {
            int c = it * 256 + w * 64 + lane;
            int row = c >> 3;
            int ksg = (c & 7) ^ (row & 7);      // pre-swizzled source
            gld_lds16(Abase + (size_t)row * HDIM + kbase + ksg * 8,
                      (char*)As + (it * 256 + w * 64) * 16);
            gld_lds16(Bbase + (size_t)row * HDIM + kbase + ksg * 8,
                      (char*)Bs + (it * 256 + w * 64) * 16);
        }
        __syncthreads();   // drains vmcnt (gld_lds) before frag reads

        bf16x8 af[2][4], bfr[2][4];
        #pragma unroll
        for (int kk = 0; kk < 2; ++kk) {
            #pragma unroll
            for (int m = 0; m < 4; ++m) {
                int row = wr*64 + m*16 + l16;
                int byte = (row*128 + kk*64 + lhi*16) ^ ((row & 7) << 4);
                af[kk][m] = *(const bf16x8*)((const char*)As + byte);
            }
            #pragma unroll
            for (int n = 0; n < 4; ++n) {
                int row = wc*64 + n*16 + l16;
                int byte = (row*128 + kk*64 + lhi*16) ^ ((row & 7) << 4);
                bfr[kk][n] = *(const bf16x8*)((const char*)Bs + byte);
            }
        }
        #pragma unroll
        for (int kk = 0; kk < 2; ++kk)
            #pragma unroll
            for (int m = 0; m < 4; ++m)
                #pragma unroll
                for (int n = 0; n < 4; ++n)
                    acc[m][n] = __builtin_amdgcn_mfma_f32_16x16x32_bf16(
                        af[kk][m], bfr[kk][n], acc[m][n], 0, 0, 0);
        __syncthreads();   // frag reads done before next stage overwrites
    }

    // Epilogue: per-token sum of exp(logit + bias) over 128 cols.
    // C/D: col = lane&15, row = (lane>>4)*4 + j
    float bv[4];
    #pragma unroll
    for (int n = 0; n < 4; ++n)
        bv[n] = Bi[tn*BN + wc*64 + n*16 + l16];

    #pragma unroll
    for (int m = 0; m < 4; ++m) {
        #pragma unroll
        for (int j = 0; j < 4; ++j) {
            float s = 0.f;
            #pragma unroll
            for (int n = 0; n < 4; ++n)
                s += __expf(acc[m][n][j] + bv[n]);
            s += __shfl_xor(s, 1);
            s += __shfl_xor(s, 2);
            s += __shfl_xor(s, 4);
            s += __shfl_xor(s, 8);
            if (l16 == 0)
                red[wc][wr*64 + m*16 + lhi*4 + j] = s;
        }
    }
    __syncthreads();
    if (tid < BM) {
        float s = red[0][tid] + red[1][tid];
        partial[((size_t)model*NT + tn)*TTOK + tm*BM + tid] = s;
    }
}

// ---------------- fallback GEMM (inline convert, explicit swizzle) ---------
__global__ __launch_bounds__(256) void gemm_expsum_f32(
    const float* __restrict__ X0, const float* __restrict__ W0, const float* __restrict__ B0,
    const float* __restrict__ X1, const float* __restrict__ W1, const float* __restrict__ B1,
    float* __restrict__ partial)
{
    const int model = blockIdx.z;
    const float* __restrict__ X = model ? X1 : X0;
    const float* __restrict__ W = model ? W1 : W0;
    const float* __restrict__ Bi = model ? B1 : B0;
    const int tm = blockIdx.x;
    const int tn = blockIdx.y;

    __shared__ short As[BM*BK];
    __shared__ short Bs[BN*BK];
    __shared__ float red[2][BM];

    const int tid  = threadIdx.x;
    const int lane = tid & 63;
    const int w    = tid >> 6;
    const int wr   = w >> 1, wc = w & 1;
    const int l16  = lane & 15, lhi = lane >> 4;

    f32x4 acc[4][4];
    #pragma unroll
    for (int m = 0; m < 4; ++m)
        #pragma unroll
        for (int n = 0; n < 4; ++n)
            acc[m][n] = (f32x4)0.f;

    for (int ks = 0; ks < KSTEPS; ++ks) {
        __syncthreads();
        const int kbase = ks * BK;
        #pragma unroll
        for (int it = 0; it < 4; ++it) {
            int s = tid + it * 256;
            int row = s >> 3, kseg = s & 7;
            const float* g = X + (size_t)(tm*BM + row)*HDIM + kbase + kseg*8;
            f32x4 v0 = *(const f32x4*)g;
            f32x4 v1 = *(const f32x4*)(g + 4);
            bf16x8 b;
            b[0]=f2bf(v0[0]); b[1]=f2bf(v0[1]); b[2]=f2bf(v0[2]); b[3]=f2bf(v0[3]);
            b[4]=f2bf(v1[0]); b[5]=f2bf(v1[1]); b[6]=f2bf(v1[2]); b[7]=f2bf(v1[3]);
            int byte = (row*128 + kseg*16) ^ ((row & 7) << 4);
            *(bf16x8*)((char*)As + byte) = b;
        }
        #pragma unroll
        for (int it = 0; it < 4; ++it) {
            int s = tid + it * 256;
            int row = s >> 3, kseg = s & 7;
            const float* g = W + (size_t)(tn*BN + row)*HDIM + kbase + kseg*8;
            f32x4 v0 = *(const f32x4*)g;
            f32x4 v1 = *(const f32x4*)(g + 4);
            bf16x8 b;
            b[0]=f2bf(v0[0]); b[1]=f2bf(v0[1]); b[2]=f2bf(v0[2]); b[3]=f2bf(v0[3]);
            b[4]=f2bf(v1[0]); b[5]=f2bf(v1[1]); b[6]=f2bf(v1[2]); b[7]=f2bf(v1[3]);
            int byte = (row*128 + kseg*16) ^ ((row & 7) << 4);
            *(bf16x8*)((char*)Bs + byte) = b;
        }
        __syncthreads();

        bf16x8 af[2][4], bfr[2][4];
        #pragma unroll
        for (int kk = 0; kk < 2; ++kk) {
            #pragma unroll
            for (int m = 0; m < 4; ++m) {
                int row = wr*64 + m*16 + l16;
                int byte = (row*128 + kk*64 + lhi*16) ^ ((row & 7) << 4);
                af[kk][m] = *(const bf16x8*)((const char*)As + byte);
            }
            #pragma unroll
            for (int n = 0; n < 4; ++n) {
                int row = wc*64 + n*16 + l16;
                int byte = (row*128 + kk*64 + lhi*16) ^ ((row & 7) << 4);
                bfr[kk][n] = *(const bf16x8*)((const char*)Bs + byte);
            }
        }
        #pragma unroll
        for (int kk = 0; kk < 2; ++kk)
            #pragma unroll
            for (int m = 0; m < 4; ++m)
                #pragma unroll
                for (int n = 0; n < 4; ++n)
                    acc[m][n] = __builtin_amdgcn_mfma_f32_16x16x32_bf16(
                        af[kk][m], bfr[kk][n], acc[m][n], 0, 0, 0);
    }

    float bv[4];
    #pragma unroll
    for (int n = 0; n < 4; ++n)
        bv[n] = Bi[tn*BN + wc*64 + n*16 + l16];

    #pragma unroll
    for (int m = 0; m < 4; ++m) {
        #pragma unroll
        for (int j = 0; j < 4; ++j) {
            float s = 0.f;
            #pragma unroll
            for (int n = 0; n < 4; ++n)
                s += __expf(acc[m][n][j] + bv[n]);
            s += __shfl_xor(s, 1);
            s += __shfl_xor(s, 2);
            s += __shfl_xor(s, 4);
            s += __shfl_xor(s, 8);
            if (l16 == 0)
                red[wc][wr*64 + m*16 + lhi*4 + j] = s;
        }
    }
    __syncthreads();
    if (tid < BM) {
        float s = red[0][tid] + red[1][tid];
        partial[((size_t)model*NT + tn)*TTOK + tm*BM + tid] = s;
    }
}

// fallback tgt (standalone)
__global__ __launch_bounds__(256) void tgt_kernel(
    const float* __restrict__ X0, const float* __restrict__ W0, const float* __restrict__ B0,
    const float* __restrict__ X1, const float* __restrict__ W1, const float* __restrict__ B1,
    const int* __restrict__ target, float* __restrict__ tgt)
{
    int gw = blockIdx.x * 4 + (threadIdx.x >> 6);
    int lane = threadIdx.x & 63;
    int model = gw >> 11;
    int t = gw & (TTOK - 1);
    const float* X = model ? X1 : X0;
    const float* W = model ? W1 : W0;
    const float* Bi = model ? B1 : B0;
    int tg = target[t];
    int stg = tg < 0 ? 0 : (tg >= VOCAB ? VOCAB - 1 : tg);
    const float* xr = X + (size_t)t * HDIM;
    const float* wrow = W + (size_t)stg * HDIM;
    float s = 0.f;
    #pragma unroll
    for (int i = 0; i < 4; ++i) {
        int k = i * 256 + lane * 4;
        f32x4 xv = *(const f32x4*)(xr + k);
        f32x4 wv = *(const f32x4*)(wrow + k);
        s += xv[0]*wv[0] + xv[1]*wv[1] + xv[2]*wv[2] + xv[3]*wv[3];
    }
    s += __shfl_xor(s, 1);  s += __shfl_xor(s, 2);  s += __shfl_xor(s, 4);
    s += __shfl_xor(s, 8);  s += __shfl_xor(s, 16); s += __shfl_xor(s, 32);
    if (lane == 0)
        tgt[model * TTOK + t] = s + Bi[stg];
}

// ---------------- coalesced logZ reduction (nt = #vocab tiles) -------------
__global__ __launch_bounds__(256) void logz_kernel(
    const float* __restrict__ partial, const float* __restrict__ tgt,
    const int* __restrict__ target, float* __restrict__ tok_lp, int nt)
{
    int g = blockIdx.x * 256 + threadIdx.x;   // 0..4095
    int m = g >> 11;
    int t = g & (TTOK - 1);
    const float* p = partial + (size_t)m * nt * TTOK + t;
    float S = 0.f;
    for (int j = 0; j < nt; ++j) S += p[(size_t)j * TTOK];
    float lp = tgt[g] - __logf(S);
    if (target[t] == -100) lp = 0.f;
    tok_lp[g] = lp;
}

// ---------------- per-seq sums + DPO loss ----------------------------------
__global__ __launch_bounds__(512) void loss_kernel(
    const float* __restrict__ tok_lp, float* __restrict__ out)
{
    int tid = threadIdx.x;
    float acc = 0.f;
    #pragma unroll
    for (int i = 0; i < 8; ++i)
        acc += tok_lp[tid * 8 + i];
    acc += __shfl_xor(acc, 1);  acc += __shfl_xor(acc, 2);
    acc += __shfl_xor(acc, 4);  acc += __shfl_xor(acc, 8);
    acc += __shfl_xor(acc, 16);
    __shared__ float ps[16];
    if ((tid & 31) == 0) ps[tid >> 5] = acc;
    __syncthreads();
    if (tid == 0) {
        float loss = 0.f;
        #pragma unroll
        for (int p = 0; p < NPAIRS; ++p) {
            float cho = ps[2*p]     - ps[8 + 2*p];
            float rej = ps[2*p + 1] - ps[8 + 2*p + 1];
            float z = BETAF * (cho - rej);
            float lsig = fminf(z, 0.f) - log1pf(__expf(-fabsf(z)));
            loss += -lsig;
        }
        out[0] = loss / (float)NPAIRS;
    }
}

// fallback finalize: single block, NT=250 layout
__global__ __launch_bounds__(512) void finalize_kernel(
    const float* __restrict__ partial, const float* __restrict__ tgt,
    const int* __restrict__ target, float* __restrict__ out)
{
    int tid = threadIdx.x;
    float acc = 0.f;
    #pragma unroll
    for (int i = 0; i < 8; ++i) {
        int g = tid * 8 + i;
        int model = g >> 11;
        int t = g & (TTOK - 1);
        const float* p = partial + (size_t)model * NT * TTOK + t;
        float S = 0.f;
        for (int j = 0; j < NT; ++j) S += p[(size_t)j * TTOK];
        float lp = tgt[g] - __logf(S);
        if (target[t] == -100) lp = 0.f;
        acc += lp;
    }
    acc += __shfl_xor(acc, 1);  acc += __shfl_xor(acc, 2);
    acc += __shfl_xor(acc, 4);  acc += __shfl_xor(acc, 8);
    acc += __shfl_xor(acc, 16);
    __shared__ float ps[16];
    if ((tid & 31) == 0) ps[tid >> 5] = acc;
    __syncthreads();
    if (tid == 0) {
        float loss = 0.f;
        #pragma unroll
        for (int p = 0; p < NPAIRS; ++p) {
            float cho = ps[2*p]     - ps[8 + 2*p];
            float rej = ps[2*p + 1] - ps[8 + 2*p + 1];
            float z = BETAF * (cho - rej);
            float lsig = fminf(z, 0.f) - log1pf(__expf(-fabsf(z)));
            loss += -lsig;
        }
        out[0] = loss / (float)NPAIRS;
    }
}

extern "C" void kernel_launch(void* const* d_in, const int* in_sizes, int n_in,
                              void* d_out, int out_size, void* d_ws, size_t ws_size,
                              hipStream_t stream) {
    const float* x    = (const float*)d_in[0];
    const float* wgt  = (const float*)d_in[1];
    const float* bias = (const float*)d_in[2];
    const float* rx   = (const float*)d_in[3];
    const float* rwgt = (const float*)d_in[4];
    const float* rb   = (const float*)d_in[5];
    const int* target = (const int*)d_in[6];
    float* out = (float*)d_out;

    // ws layout
    float* partial = (float*)d_ws;                       // 2*250*2048 f = 4 MB
    float* tgtb    = partial + (size_t)2 * NT * TTOK;    // 4096 f
    float* tok_lp  = tgtb + 2 * TTOK;                    // 4096 f
    short* Xb      = (short*)(tok_lp + 2 * TTOK);        // 8 MB
    short* Wb      = Xb + (size_t)2 * TTOK * HDIM;       // 131 MB
    size_t need = (size_t)((char*)(Wb + (size_t)2 * VOCAB * HDIM) - (char*)d_ws);

    if (ws_size >= need) {
        prep_kernel<<<CONV_BLOCKS + TGT_BLOCKS, 256, 0, stream>>>(
            x, rx, wgt, rwgt, bias, rb, Xb, Wb, target, tgtb);
        gemm_expsum_bf16<<<NWG, 256, 0, stream>>>(Xb, Wb, bias, rb, partial);
        logz_kernel<<<16, 256, 0, stream>>>(partial, tgtb, target, tok_lp, NT);
        loss_kernel<<<1, 512, 0, stream>>>(tok_lp, out);
    } else {
        dim3 grid(MT, NT, 2);
        gemm_expsum_f32<<<grid, 256, 0, stream>>>(x, wgt, bias, rx, rwgt, rb, partial);
        tgt_kernel<<<(2 * TTOK) / 4, 256, 0, stream>>>(x, wgt, bias, rx, rwgt, rb, target, tgtb);
        finalize_kernel<<<1, 512, 0, stream>>>(partial, tgtb, target, out);
    }
}

// Round 8
// 405.559 us; speedup vs baseline: 1.1104x; 1.0092x over previous
//
#include <hip/hip_runtime.h>
#include <hip/hip_bf16.h>

#define HDIM 1024
#define VOCAB 32000
#define TTOK 2048
#define BETAF 0.1f
#define NPAIRS 4

#define BM 128
#define BN 128
#define BK 64
#define MT (TTOK/BM)     // 16
#define NT (VOCAB/BN)    // 250
#define KSTEPS (HDIM/BK) // 16
#define NWG (MT*NT*2)    // 8000, %8==0

#define CONV_BLOCKS 2048   // uniform grid; tgt folded into waves 0-1

typedef __attribute__((ext_vector_type(4))) float f32x4;
typedef __attribute__((ext_vector_type(8))) short bf16x8;

__device__ __forceinline__ short f2bf(float f) {
    union { float f; unsigned u; } v; v.f = f;
    return (short)((v.u + 0x7FFFu + ((v.u >> 16) & 1u)) >> 16);  // RNE
}

__device__ __forceinline__ void gld_lds16(const void* g, void* l) {
    __builtin_amdgcn_global_load_lds(
        (const __attribute__((address_space(1))) unsigned int*)g,
        (__attribute__((address_space(3))) unsigned int*)l, 16, 0, 0);
}

// ---------------- fused prep: tgt dots (waves 0-1) + fp32->bf16 convert ----
// Uniform 2048-block grid: block b, waves 0-1 first compute tgt task b*2+wid
// (exact fp32 target logit), then ALL waves run the grid-stride convert of
// {x, rx, wgt, rwgt}. No straggler tail (was: separate 1024-block tgt pass).
__global__ __launch_bounds__(256) void prep_kernel(
    const float* __restrict__ x,    const float* __restrict__ rx,
    const float* __restrict__ wgt,  const float* __restrict__ rwgt,
    const float* __restrict__ bias, const float* __restrict__ rb,
    short* __restrict__ Xb, short* __restrict__ Wb,
    const int* __restrict__ target, float* __restrict__ tgt)
{
    const int b = blockIdx.x;
    const int wid = threadIdx.x >> 6;
    const int lane = threadIdx.x & 63;

    if (wid < 2) {
        int gw = b * 2 + wid;                 // 0..4095 (model, token) tasks
        int model = gw >> 11;
        int t = gw & (TTOK - 1);
        const float* X  = model ? rx : x;
        const float* W  = model ? rwgt : wgt;
        const float* Bi = model ? rb : bias;
        int tg = target[t];
        int stg = tg < 0 ? 0 : (tg >= VOCAB ? VOCAB - 1 : tg);
        const float* xr = X + (size_t)t * HDIM;
        const float* wrow = W + (size_t)stg * HDIM;
        float s = 0.f;
        #pragma unroll
        for (int i = 0; i < 4; ++i) {
            int k = i * 256 + lane * 4;
            f32x4 xv = *(const f32x4*)(xr + k);
            f32x4 wv = *(const f32x4*)(wrow + k);
            s += xv[0]*wv[0] + xv[1]*wv[1] + xv[2]*wv[2] + xv[3]*wv[3];
        }
        s += __shfl_xor(s, 1);  s += __shfl_xor(s, 2);  s += __shfl_xor(s, 4);
        s += __shfl_xor(s, 8);  s += __shfl_xor(s, 16); s += __shfl_xor(s, 32);
        if (lane == 0)
            tgt[model * TTOK + t] = s + Bi[stg];
    }

    const int XN8 = TTOK * HDIM / 8;      // 262144
    const int WN8 = VOCAB * HDIM / 8;     // 4096000
    const int TOT = 2 * XN8 + 2 * WN8;    // 8716288
    const int stride = CONV_BLOCKS * 256;
    for (int i = b * 256 + threadIdx.x; i < TOT; i += stride) {
        const float* src; short* dst; int off;
        if (i < XN8)            { src = x;    dst = Xb;                          off = i; }
        else if (i < 2*XN8)     { src = rx;   dst = Xb + (size_t)TTOK*HDIM;      off = i - XN8; }
        else if (i < 2*XN8+WN8) { src = wgt;  dst = Wb;                          off = i - 2*XN8; }
        else                    { src = rwgt; dst = Wb + (size_t)VOCAB*HDIM;     off = i - 2*XN8 - WN8; }
        size_t e = (size_t)off * 8;
        f32x4 v0 = *(const f32x4*)(src + e);
        f32x4 v1 = *(const f32x4*)(src + e + 4);
        bf16x8 o;
        o[0]=f2bf(v0[0]); o[1]=f2bf(v0[1]); o[2]=f2bf(v0[2]); o[3]=f2bf(v0[3]);
        o[4]=f2bf(v1[0]); o[5]=f2bf(v1[1]); o[6]=f2bf(v1[2]); o[7]=f2bf(v1[3]);
        *(bf16x8*)(dst + e) = o;
    }
}

// ---------------- main GEMM: round-3 kernel (~950 TF, m97-structure) -------
// Layout invariant (rule #21): LDS dest linear (gld_lds writes base+lane*16);
// global source pre-swizzled kseg^=(row&7); reads XOR the same involution.
__global__ __launch_bounds__(256, 4) void gemm_expsum_bf16(
    const short* __restrict__ Xb, const short* __restrict__ Wb,
    const float* __restrict__ B0, const float* __restrict__ B1,
    float* __restrict__ partial)
{
    // T1: bijective XCD swizzle (NWG % 8 == 0), tm fastest for W-panel reuse
    int raw = blockIdx.x;
    int swz = (raw & 7) * (NWG / 8) + (raw >> 3);
    const int model = swz / (MT * NT);
    int rem = swz % (MT * NT);
    const int tn = rem / MT;
    const int tm = rem % MT;

    const short* __restrict__ X = Xb + (size_t)model * TTOK * HDIM;
    const short* __restrict__ W = Wb + (size_t)model * VOCAB * HDIM;
    const float* __restrict__ Bi = model ? B1 : B0;

    __shared__ short As[BM*BK];   // 16 KB
    __shared__ short Bs[BN*BK];   // 16 KB
    __shared__ float red[2][BM];

    const int tid  = threadIdx.x;
    const int lane = tid & 63;
    const int w    = tid >> 6;
    const int wr   = w >> 1, wc = w & 1;    // 2x2 waves, 64x64 out each
    const int l16  = lane & 15, lhi = lane >> 4;

    f32x4 acc[4][4];
    #pragma unroll
    for (int m = 0; m < 4; ++m)
        #pragma unroll
        for (int n = 0; n < 4; ++n)
            acc[m][n] = (f32x4)0.f;

    const short* Abase = X + (size_t)tm * BM * HDIM;
    const short* Bbase = W + (size_t)tn * BN * HDIM;

    for (int ks = 0; ks < KSTEPS; ++ks) {
        const int kbase = ks * BK;
        // stage: 1024 x 16B chunks per tile. Linear LDS slot c holds global
        // chunk (row = c>>3, kseg = (c&7) ^ (row&7)).
        #pragma unroll
        for (int it = 0; it < 4; ++it) {
            int c = it * 256 + w * 64 + lane;
            int row = c >> 3;
            int ksg = (c & 7) ^ (row & 7);      // pre-swizzled source
            gld_lds16(Abase + (size_t)row * HDIM + kbase + ksg * 8,
                      (char*)As + (it * 256 + w * 64) * 16);
            gld_lds16(Bbase + (size_t)row * HDIM + kbase + ksg * 8,
                      (char*)Bs + (it * 256 + w * 64) * 16);
        }
        __syncthreads();   // drains vmcnt (gld_lds) before frag reads

        bf16x8 af[2][4], bfr[2][4];
        #pragma unroll
        for (int kk = 0; kk < 2; ++kk) {
            #pragma unroll
            for (int m = 0; m < 4; ++m) {
                int row = wr*64 + m*16 + l16;
                int byte = (row*128 + kk*64 + lhi*16) ^ ((row & 7) << 4);
                af[kk][m] = *(const bf16x8*)((const char*)As + byte);
            }
            #pragma unroll
            for (int n = 0; n < 4; ++n) {
                int row = wc*64 + n*16 + l16;
                int byte = (row*128 + kk*64 + lhi*16) ^ ((row & 7) << 4);
                bfr[kk][n] = *(const bf16x8*)((const char*)Bs + byte);
            }
        }
        #pragma unroll
        for (int kk = 0; kk < 2; ++kk)
            #pragma unroll
            for (int m = 0; m < 4; ++m)
                #pragma unroll
                for (int n = 0; n < 4; ++n)
                    acc[m][n] = __builtin_amdgcn_mfma_f32_16x16x32_bf16(
                        af[kk][m], bfr[kk][n], acc[m][n], 0, 0, 0);
        __syncthreads();   // frag reads done before next stage overwrites
    }

    // Epilogue: per-token sum of exp(logit + bias) over 128 cols.
    // C/D: col = lane&15, row = (lane>>4)*4 + j
    float bv[4];
    #pragma unroll
    for (int n = 0; n < 4; ++n)
        bv[n] = Bi[tn*BN + wc*64 + n*16 + l16];

    #pragma unroll
    for (int m = 0; m < 4; ++m) {
        #pragma unroll
        for (int j = 0; j < 4; ++j) {
            float s = 0.f;
            #pragma unroll
            for (int n = 0; n < 4; ++n)
                s += __expf(acc[m][n][j] + bv[n]);
            s += __shfl_xor(s, 1);
            s += __shfl_xor(s, 2);
            s += __shfl_xor(s, 4);
            s += __shfl_xor(s, 8);
            if (l16 == 0)
                red[wc][wr*64 + m*16 + lhi*4 + j] = s;
        }
    }
    __syncthreads();
    if (tid < BM) {
        float s = red[0][tid] + red[1][tid];
        partial[((size_t)model*NT + tn)*TTOK + tm*BM + tid] = s;
    }
}

// ---------------- fallback GEMM (inline convert, explicit swizzle) ---------
__global__ __launch_bounds__(256) void gemm_expsum_f32(
    const float* __restrict__ X0, const float* __restrict__ W0, const float* __restrict__ B0,
    const float* __restrict__ X1, const float* __restrict__ W1, const float* __restrict__ B1,
    float* __restrict__ partial)
{
    const int model = blockIdx.z;
    const float* __restrict__ X = model ? X1 : X0;
    const float* __restrict__ W = model ? W1 : W0;
    const float* __restrict__ Bi = model ? B1 : B0;
    const int tm = blockIdx.x;
    const int tn = blockIdx.y;

    __shared__ short As[BM*BK];
    __shared__ short Bs[BN*BK];
    __shared__ float red[2][BM];

    const int tid  = threadIdx.x;
    const int lane = tid & 63;
    const int w    = tid >> 6;
    const int wr   = w >> 1, wc = w & 1;
    const int l16  = lane & 15, lhi = lane >> 4;

    f32x4 acc[4][4];
    #pragma unroll
    for (int m = 0; m < 4; ++m)
        #pragma unroll
        for (int n = 0; n < 4; ++n)
            acc[m][n] = (f32x4)0.f;

    for (int ks = 0; ks < KSTEPS; ++ks) {
        __syncthreads();
        const int kbase = ks * BK;
        #pragma unroll
        for (int it = 0; it < 4; ++it) {
            int s = tid + it * 256;
            int row = s >> 3, kseg = s & 7;
            const float* g = X + (size_t)(tm*BM + row)*HDIM + kbase + kseg*8;
            f32x4 v0 = *(const f32x4*)g;
            f32x4 v1 = *(const f32x4*)(g + 4);
            bf16x8 b;
            b[0]=f2bf(v0[0]); b[1]=f2bf(v0[1]); b[2]=f2bf(v0[2]); b[3]=f2bf(v0[3]);
            b[4]=f2bf(v1[0]); b[5]=f2bf(v1[1]); b[6]=f2bf(v1[2]); b[7]=f2bf(v1[3]);
            int byte = (row*128 + kseg*16) ^ ((row & 7) << 4);
            *(bf16x8*)((char*)As + byte) = b;
        }
        #pragma unroll
        for (int it = 0; it < 4; ++it) {
            int s = tid + it * 256;
            int row = s >> 3, kseg = s & 7;
            const float* g = W + (size_t)(tn*BN + row)*HDIM + kbase + kseg*8;
            f32x4 v0 = *(const f32x4*)g;
            f32x4 v1 = *(const f32x4*)(g + 4);
            bf16x8 b;
            b[0]=f2bf(v0[0]); b[1]=f2bf(v0[1]); b[2]=f2bf(v0[2]); b[3]=f2bf(v0[3]);
            b[4]=f2bf(v1[0]); b[5]=f2bf(v1[1]); b[6]=f2bf(v1[2]); b[7]=f2bf(v1[3]);
            int byte = (row*128 + kseg*16) ^ ((row & 7) << 4);
            *(bf16x8*)((char*)Bs + byte) = b;
        }
        __syncthreads();

        bf16x8 af[2][4], bfr[2][4];
        #pragma unroll
        for (int kk = 0; kk < 2; ++kk) {
            #pragma unroll
            for (int m = 0; m < 4; ++m) {
                int row = wr*64 + m*16 + l16;
                int byte = (row*128 + kk*64 + lhi*16) ^ ((row & 7) << 4);
                af[kk][m] = *(const bf16x8*)((const char*)As + byte);
            }
            #pragma unroll
            for (int n = 0; n < 4; ++n) {
                int row = wc*64 + n*16 + l16;
                int byte = (row*128 + kk*64 + lhi*16) ^ ((row & 7) << 4);
                bfr[kk][n] = *(const bf16x8*)((const char*)Bs + byte);
            }
        }
        #pragma unroll
        for (int kk = 0; kk < 2; ++kk)
            #pragma unroll
            for (int m = 0; m < 4; ++m)
                #pragma unroll
                for (int n = 0; n < 4; ++n)
                    acc[m][n] = __builtin_amdgcn_mfma_f32_16x16x32_bf16(
                        af[kk][m], bfr[kk][n], acc[m][n], 0, 0, 0);
    }

    float bv[4];
    #pragma unroll
    for (int n = 0; n < 4; ++n)
        bv[n] = Bi[tn*BN + wc*64 + n*16 + l16];

    #pragma unroll
    for (int m = 0; m < 4; ++m) {
        #pragma unroll
        for (int j = 0; j < 4; ++j) {
            float s = 0.f;
            #pragma unroll
            for (int n = 0; n < 4; ++n)
                s += __expf(acc[m][n][j] + bv[n]);
            s += __shfl_xor(s, 1);
            s += __shfl_xor(s, 2);
            s += __shfl_xor(s, 4);
            s += __shfl_xor(s, 8);
            if (l16 == 0)
                red[wc][wr*64 + m*16 + lhi*4 + j] = s;
        }
    }
    __syncthreads();
    if (tid < BM) {
        float s = red[0][tid] + red[1][tid];
        partial[((size_t)model*NT + tn)*TTOK + tm*BM + tid] = s;
    }
}

// fallback tgt (standalone)
__global__ __launch_bounds__(256) void tgt_kernel(
    const float* __restrict__ X0, const float* __restrict__ W0, const float* __restrict__ B0,
    const float* __restrict__ X1, const float* __restrict__ W1, const float* __restrict__ B1,
    const int* __restrict__ target, float* __restrict__ tgt)
{
    int gw = blockIdx.x * 4 + (threadIdx.x >> 6);
    int lane = threadIdx.x & 63;
    int model = gw >> 11;
    int t = gw & (TTOK - 1);
    const float* X = model ? X1 : X0;
    const float* W = model ? W1 : W0;
    const float* Bi = model ? B1 : B0;
    int tg = target[t];
    int stg = tg < 0 ? 0 : (tg >= VOCAB ? VOCAB - 1 : tg);
    const float* xr = X + (size_t)t * HDIM;
    const float* wrow = W + (size_t)stg * HDIM;
    float s = 0.f;
    #pragma unroll
    for (int i = 0; i < 4; ++i) {
        int k = i * 256 + lane * 4;
        f32x4 xv = *(const f32x4*)(xr + k);
        f32x4 wv = *(const f32x4*)(wrow + k);
        s += xv[0]*wv[0] + xv[1]*wv[1] + xv[2]*wv[2] + xv[3]*wv[3];
    }
    s += __shfl_xor(s, 1);  s += __shfl_xor(s, 2);  s += __shfl_xor(s, 4);
    s += __shfl_xor(s, 8);  s += __shfl_xor(s, 16); s += __shfl_xor(s, 32);
    if (lane == 0)
        tgt[model * TTOK + t] = s + Bi[stg];
}

// ---------------- seq-aligned logZ + per-seq sums --------------------------
// block b (0..15) covers tokens g = b*256..+255 = exactly one (model, seq);
// writes seqsum[b] = sum of masked token logps for that sequence.
__global__ __launch_bounds__(256) void logz_kernel(
    const float* __restrict__ partial, const float* __restrict__ tgt,
    const int* __restrict__ target, float* __restrict__ seqsum, int nt)
{
    int g = blockIdx.x * 256 + threadIdx.x;   // 0..4095
    int m = g >> 11;
    int t = g & (TTOK - 1);
    const float* p = partial + (size_t)m * nt * TTOK + t;
    float S = 0.f;
    for (int j = 0; j < nt; ++j) S += p[(size_t)j * TTOK];
    float lp = tgt[g] - __logf(S);
    if (target[t] == -100) lp = 0.f;
    // block-reduce 256 values
    float acc = lp;
    acc += __shfl_xor(acc, 1);  acc += __shfl_xor(acc, 2);
    acc += __shfl_xor(acc, 4);  acc += __shfl_xor(acc, 8);
    acc += __shfl_xor(acc, 16); acc += __shfl_xor(acc, 32);
    __shared__ float ws[4];
    if ((threadIdx.x & 63) == 0) ws[threadIdx.x >> 6] = acc;
    __syncthreads();
    if (threadIdx.x == 0)
        seqsum[blockIdx.x] = ws[0] + ws[1] + ws[2] + ws[3];
}

// ---------------- DPO loss from 16 seq sums --------------------------------
// seqsum[0..7] = policy seqs (alternating chosen/rejected), [8..15] = ref.
__global__ __launch_bounds__(64) void loss_kernel(
    const float* __restrict__ seqsum, float* __restrict__ out)
{
    if (threadIdx.x == 0) {
        float loss = 0.f;
        #pragma unroll
        for (int p = 0; p < NPAIRS; ++p) {
            float cho = seqsum[2*p]     - seqsum[8 + 2*p];
            float rej = seqsum[2*p + 1] - seqsum[8 + 2*p + 1];
            float z = BETAF * (cho - rej);
            float lsig = fminf(z, 0.f) - log1pf(__expf(-fabsf(z)));
            loss += -lsig;
        }
        out[0] = loss / (float)NPAIRS;
    }
}

// fallback finalize: single block, NT=250 layout
__global__ __launch_bounds__(512) void finalize_kernel(
    const float* __restrict__ partial, const float* __restrict__ tgt,
    const int* __restrict__ target, float* __restrict__ out)
{
    int tid = threadIdx.x;
    float acc = 0.f;
    #pragma unroll
    for (int i = 0; i < 8; ++i) {
        int g = tid * 8 + i;
        int model = g >> 11;
        int t = g & (TTOK - 1);
        const float* p = partial + (size_t)model * NT * TTOK + t;
        float S = 0.f;
        for (int j = 0; j < NT; ++j) S += p[(size_t)j * TTOK];
        float lp = tgt[g] - __logf(S);
        if (target[t] == -100) lp = 0.f;
        acc += lp;
    }
    acc += __shfl_xor(acc, 1);  acc += __shfl_xor(acc, 2);
    acc += __shfl_xor(acc, 4);  acc += __shfl_xor(acc, 8);
    acc += __shfl_xor(acc, 16);
    __shared__ float ps[16];
    if ((tid & 31) == 0) ps[tid >> 5] = acc;
    __syncthreads();
    if (tid == 0) {
        float loss = 0.f;
        #pragma unroll
        for (int p = 0; p < NPAIRS; ++p) {
            float cho = ps[2*p]     - ps[8 + 2*p];
            float rej = ps[2*p + 1] - ps[8 + 2*p + 1];
            float z = BETAF * (cho - rej);
            float lsig = fminf(z, 0.f) - log1pf(__expf(-fabsf(z)));
            loss += -lsig;
        }
        out[0] = loss / (float)NPAIRS;
    }
}

extern "C" void kernel_launch(void* const* d_in, const int* in_sizes, int n_in,
                              void* d_out, int out_size, void* d_ws, size_t ws_size,
                              hipStream_t stream) {
    const float* x    = (const float*)d_in[0];
    const float* wgt  = (const float*)d_in[1];
    const float* bias = (const float*)d_in[2];
    const float* rx   = (const float*)d_in[3];
    const float* rwgt = (const float*)d_in[4];
    const float* rb   = (const float*)d_in[5];
    const int* target = (const int*)d_in[6];
    float* out = (float*)d_out;

    // ws layout
    float* partial = (float*)d_ws;                       // 2*250*2048 f = 4 MB
    float* tgtb    = partial + (size_t)2 * NT * TTOK;    // 4096 f
    float* seqsum  = tgtb + 2 * TTOK;                    // 16 f (+pad)
    short* Xb      = (short*)(seqsum + 64);              // 8 MB
    short* Wb      = Xb + (size_t)2 * TTOK * HDIM;       // 131 MB
    size_t need = (size_t)((char*)(Wb + (size_t)2 * VOCAB * HDIM) - (char*)d_ws);

    if (ws_size >= need) {
        prep_kernel<<<CONV_BLOCKS, 256, 0, stream>>>(
            x, rx, wgt, rwgt, bias, rb, Xb, Wb, target, tgtb);
        gemm_expsum_bf16<<<NWG, 256, 0, stream>>>(Xb, Wb, bias, rb, partial);
        logz_kernel<<<16, 256, 0, stream>>>(partial, tgtb, target, seqsum, NT);
        loss_kernel<<<1, 64, 0, stream>>>(seqsum, out);
    } else {
        dim3 grid(MT, NT, 2);
        gemm_expsum_f32<<<grid, 256, 0, stream>>>(x, wgt, bias, rx, rwgt, rb, partial);
        tgt_kernel<<<(2 * TTOK) / 4, 256, 0, stream>>>(x, wgt, bias, rx, rwgt, rb, target, tgtb);
        finalize_kernel<<<1, 512, 0, stream>>>(partial, tgtb, target, out);
    }
}

// Round 9
// 361.611 us; speedup vs baseline: 1.2454x; 1.1215x over previous
//
#include <hip/hip_runtime.h>
#include <hip/hip_bf16.h>

#define HDIM 1024
#define VOCAB 32000
#define TTOK 2048
#define BETAF 0.1f
#define NPAIRS 4

#define BM 128
#define BN 128
#define BK 64
#define MT (TTOK/BM)     // 16
#define NT (VOCAB/BN)    // 250
#define KSTEPS (HDIM/BK) // 16
#define NWG (MT*NT*2)    // 8000, %8==0

#define CONV_BLOCKS 2048   // uniform grid; tgt folded into waves 0-1

typedef __attribute__((ext_vector_type(4))) float f32x4;
typedef __attribute__((ext_vector_type(8))) short bf16x8;

__device__ __forceinline__ short f2bf(float f) {
    union { float f; unsigned u; } v; v.f = f;
    return (short)((v.u + 0x7FFFu + ((v.u >> 16) & 1u)) >> 16);  // RNE
}

__device__ __forceinline__ void gld_lds16(const void* g, void* l) {
    __builtin_amdgcn_global_load_lds(
        (const __attribute__((address_space(1))) unsigned int*)g,
        (__attribute__((address_space(3))) unsigned int*)l, 16, 0, 0);
}

// ---------------- fused prep: tgt dots (waves 0-1) + fp32->bf16 convert ----
__global__ __launch_bounds__(256) void prep_kernel(
    const float* __restrict__ x,    const float* __restrict__ rx,
    const float* __restrict__ wgt,  const float* __restrict__ rwgt,
    const float* __restrict__ bias, const float* __restrict__ rb,
    short* __restrict__ Xb, short* __restrict__ Wb,
    const int* __restrict__ target, float* __restrict__ tgt)
{
    const int b = blockIdx.x;
    const int wid = threadIdx.x >> 6;
    const int lane = threadIdx.x & 63;

    if (wid < 2) {
        int gw = b * 2 + wid;                 // 0..4095 (model, token) tasks
        int model = gw >> 11;
        int t = gw & (TTOK - 1);
        const float* X  = model ? rx : x;
        const float* W  = model ? rwgt : wgt;
        const float* Bi = model ? rb : bias;
        int tg = target[t];
        int stg = tg < 0 ? 0 : (tg >= VOCAB ? VOCAB - 1 : tg);
        const float* xr = X + (size_t)t * HDIM;
        const float* wrow = W + (size_t)stg * HDIM;
        float s = 0.f;
        #pragma unroll
        for (int i = 0; i < 4; ++i) {
            int k = i * 256 + lane * 4;
            f32x4 xv = *(const f32x4*)(xr + k);
            f32x4 wv = *(const f32x4*)(wrow + k);
            s += xv[0]*wv[0] + xv[1]*wv[1] + xv[2]*wv[2] + xv[3]*wv[3];
        }
        s += __shfl_xor(s, 1);  s += __shfl_xor(s, 2);  s += __shfl_xor(s, 4);
        s += __shfl_xor(s, 8);  s += __shfl_xor(s, 16); s += __shfl_xor(s, 32);
        if (lane == 0)
            tgt[model * TTOK + t] = s + Bi[stg];
    }

    const int XN8 = TTOK * HDIM / 8;      // 262144
    const int WN8 = VOCAB * HDIM / 8;     // 4096000
    const int TOT = 2 * XN8 + 2 * WN8;    // 8716288
    const int stride = CONV_BLOCKS * 256;
    for (int i = b * 256 + threadIdx.x; i < TOT; i += stride) {
        const float* src; short* dst; int off;
        if (i < XN8)            { src = x;    dst = Xb;                          off = i; }
        else if (i < 2*XN8)     { src = rx;   dst = Xb + (size_t)TTOK*HDIM;      off = i - XN8; }
        else if (i < 2*XN8+WN8) { src = wgt;  dst = Wb;                          off = i - 2*XN8; }
        else                    { src = rwgt; dst = Wb + (size_t)VOCAB*HDIM;     off = i - 2*XN8 - WN8; }
        size_t e = (size_t)off * 8;
        f32x4 v0 = *(const f32x4*)(src + e);
        f32x4 v1 = *(const f32x4*)(src + e + 4);
        bf16x8 o;
        o[0]=f2bf(v0[0]); o[1]=f2bf(v0[1]); o[2]=f2bf(v0[2]); o[3]=f2bf(v0[3]);
        o[4]=f2bf(v1[0]); o[5]=f2bf(v1[1]); o[6]=f2bf(v1[2]); o[7]=f2bf(v1[3]);
        *(bf16x8*)(dst + e) = o;
    }
}

// ---------------- main GEMM: round-3 kernel (~950 TF, m97-structure) -------
// Layout invariant (rule #21): LDS dest linear (gld_lds writes base+lane*16);
// global source pre-swizzled kseg^=(row&7); reads XOR the same involution.
__global__ __launch_bounds__(256, 4) void gemm_expsum_bf16(
    const short* __restrict__ Xb, const short* __restrict__ Wb,
    const float* __restrict__ B0, const float* __restrict__ B1,
    float* __restrict__ partial)
{
    // T1: bijective XCD swizzle (NWG % 8 == 0), tm fastest for W-panel reuse
    int raw = blockIdx.x;
    int swz = (raw & 7) * (NWG / 8) + (raw >> 3);
    const int model = swz / (MT * NT);
    int rem = swz % (MT * NT);
    const int tn = rem / MT;
    const int tm = rem % MT;

    const short* __restrict__ X = Xb + (size_t)model * TTOK * HDIM;
    const short* __restrict__ W = Wb + (size_t)model * VOCAB * HDIM;
    const float* __restrict__ Bi = model ? B1 : B0;

    __shared__ short As[BM*BK];   // 16 KB
    __shared__ short Bs[BN*BK];   // 16 KB
    __shared__ float red[2][BM];

    const int tid  = threadIdx.x;
    const int lane = tid & 63;
    const int w    = tid >> 6;
    const int wr   = w >> 1, wc = w & 1;    // 2x2 waves, 64x64 out each
    const int l16  = lane & 15, lhi = lane >> 4;

    f32x4 acc[4][4];
    #pragma unroll
    for (int m = 0; m < 4; ++m)
        #pragma unroll
        for (int n = 0; n < 4; ++n)
            acc[m][n] = (f32x4)0.f;

    const short* Abase = X + (size_t)tm * BM * HDIM;
    const short* Bbase = W + (size_t)tn * BN * HDIM;

    for (int ks = 0; ks < KSTEPS; ++ks) {
        const int kbase = ks * BK;
        #pragma unroll
        for (int it = 0; it < 4; ++it) {
            int c = it * 256 + w * 64 + lane;
            int row = c >> 3;
            int ksg = (c & 7) ^ (row & 7);      // pre-swizzled source
            gld_lds16(Abase + (size_t)row * HDIM + kbase + ksg * 8,
                      (char*)As + (it * 256 + w * 64) * 16);
            gld_lds16(Bbase + (size_t)row * HDIM + kbase + ksg * 8,
                      (char*)Bs + (it * 256 + w * 64) * 16);
        }
        __syncthreads();   // drains vmcnt (gld_lds) before frag reads

        bf16x8 af[2][4], bfr[2][4];
        #pragma unroll
        for (int kk = 0; kk < 2; ++kk) {
            #pragma unroll
            for (int m = 0; m < 4; ++m) {
                int row = wr*64 + m*16 + l16;
                int byte = (row*128 + kk*64 + lhi*16) ^ ((row & 7) << 4);
                af[kk][m] = *(const bf16x8*)((const char*)As + byte);
            }
            #pragma unroll
            for (int n = 0; n < 4; ++n) {
                int row = wc*64 + n*16 + l16;
                int byte = (row*128 + kk*64 + lhi*16) ^ ((row & 7) << 4);
                bfr[kk][n] = *(const bf16x8*)((const char*)Bs + byte);
            }
        }
        #pragma unroll
        for (int kk = 0; kk < 2; ++kk)
            #pragma unroll
            for (int m = 0; m < 4; ++m)
                #pragma unroll
                for (int n = 0; n < 4; ++n)
                    acc[m][n] = __builtin_amdgcn_mfma_f32_16x16x32_bf16(
                        af[kk][m], bfr[kk][n], acc[m][n], 0, 0, 0);
        __syncthreads();   // frag reads done before next stage overwrites
    }

    // Epilogue: per-token sum of exp(logit + bias) over 128 cols.
    float bv[4];
    #pragma unroll
    for (int n = 0; n < 4; ++n)
        bv[n] = Bi[tn*BN + wc*64 + n*16 + l16];

    #pragma unroll
    for (int m = 0; m < 4; ++m) {
        #pragma unroll
        for (int j = 0; j < 4; ++j) {
            float s = 0.f;
            #pragma unroll
            for (int n = 0; n < 4; ++n)
                s += __expf(acc[m][n][j] + bv[n]);
            s += __shfl_xor(s, 1);
            s += __shfl_xor(s, 2);
            s += __shfl_xor(s, 4);
            s += __shfl_xor(s, 8);
            if (l16 == 0)
                red[wc][wr*64 + m*16 + lhi*4 + j] = s;
        }
    }
    __syncthreads();
    if (tid < BM) {
        float s = red[0][tid] + red[1][tid];
        partial[((size_t)model*NT + tn)*TTOK + tm*BM + tid] = s;
    }
}

// ---------------- fallback GEMM (inline convert, explicit swizzle) ---------
__global__ __launch_bounds__(256) void gemm_expsum_f32(
    const float* __restrict__ X0, const float* __restrict__ W0, const float* __restrict__ B0,
    const float* __restrict__ X1, const float* __restrict__ W1, const float* __restrict__ B1,
    float* __restrict__ partial)
{
    const int model = blockIdx.z;
    const float* __restrict__ X = model ? X1 : X0;
    const float* __restrict__ W = model ? W1 : W0;
    const float* __restrict__ Bi = model ? B1 : B0;
    const int tm = blockIdx.x;
    const int tn = blockIdx.y;

    __shared__ short As[BM*BK];
    __shared__ short Bs[BN*BK];
    __shared__ float red[2][BM];

    const int tid  = threadIdx.x;
    const int lane = tid & 63;
    const int w    = tid >> 6;
    const int wr   = w >> 1, wc = w & 1;
    const int l16  = lane & 15, lhi = lane >> 4;

    f32x4 acc[4][4];
    #pragma unroll
    for (int m = 0; m < 4; ++m)
        #pragma unroll
        for (int n = 0; n < 4; ++n)
            acc[m][n] = (f32x4)0.f;

    for (int ks = 0; ks < KSTEPS; ++ks) {
        __syncthreads();
        const int kbase = ks * BK;
        #pragma unroll
        for (int it = 0; it < 4; ++it) {
            int s = tid + it * 256;
            int row = s >> 3, kseg = s & 7;
            const float* g = X + (size_t)(tm*BM + row)*HDIM + kbase + kseg*8;
            f32x4 v0 = *(const f32x4*)g;
            f32x4 v1 = *(const f32x4*)(g + 4);
            bf16x8 b;
            b[0]=f2bf(v0[0]); b[1]=f2bf(v0[1]); b[2]=f2bf(v0[2]); b[3]=f2bf(v0[3]);
            b[4]=f2bf(v1[0]); b[5]=f2bf(v1[1]); b[6]=f2bf(v1[2]); b[7]=f2bf(v1[3]);
            int byte = (row*128 + kseg*16) ^ ((row & 7) << 4);
            *(bf16x8*)((char*)As + byte) = b;
        }
        #pragma unroll
        for (int it = 0; it < 4; ++it) {
            int s = tid + it * 256;
            int row = s >> 3, kseg = s & 7;
            const float* g = W + (size_t)(tn*BN + row)*HDIM + kbase + kseg*8;
            f32x4 v0 = *(const f32x4*)g;
            f32x4 v1 = *(const f32x4*)(g + 4);
            bf16x8 b;
            b[0]=f2bf(v0[0]); b[1]=f2bf(v0[1]); b[2]=f2bf(v0[2]); b[3]=f2bf(v0[3]);
            b[4]=f2bf(v1[0]); b[5]=f2bf(v1[1]); b[6]=f2bf(v1[2]); b[7]=f2bf(v1[3]);
            int byte = (row*128 + kseg*16) ^ ((row & 7) << 4);
            *(bf16x8*)((char*)Bs + byte) = b;
        }
        __syncthreads();

        bf16x8 af[2][4], bfr[2][4];
        #pragma unroll
        for (int kk = 0; kk < 2; ++kk) {
            #pragma unroll
            for (int m = 0; m < 4; ++m) {
                int row = wr*64 + m*16 + l16;
                int byte = (row*128 + kk*64 + lhi*16) ^ ((row & 7) << 4);
                af[kk][m] = *(const bf16x8*)((const char*)As + byte);
            }
            #pragma unroll
            for (int n = 0; n < 4; ++n) {
                int row = wc*64 + n*16 + l16;
                int byte = (row*128 + kk*64 + lhi*16) ^ ((row & 7) << 4);
                bfr[kk][n] = *(const bf16x8*)((const char*)Bs + byte);
            }
        }
        #pragma unroll
        for (int kk = 0; kk < 2; ++kk)
            #pragma unroll
            for (int m = 0; m < 4; ++m)
                #pragma unroll
                for (int n = 0; n < 4; ++n)
                    acc[m][n] = __builtin_amdgcn_mfma_f32_16x16x32_bf16(
                        af[kk][m], bfr[kk][n], acc[m][n], 0, 0, 0);
    }

    float bv[4];
    #pragma unroll
    for (int n = 0; n < 4; ++n)
        bv[n] = Bi[tn*BN + wc*64 + n*16 + l16];

    #pragma unroll
    for (int m = 0; m < 4; ++m) {
        #pragma unroll
        for (int j = 0; j < 4; ++j) {
            float s = 0.f;
            #pragma unroll
            for (int n = 0; n < 4; ++n)
                s += __expf(acc[m][n][j] + bv[n]);
            s += __shfl_xor(s, 1);
            s += __shfl_xor(s, 2);
            s += __shfl_xor(s, 4);
            s += __shfl_xor(s, 8);
            if (l16 == 0)
                red[wc][wr*64 + m*16 + lhi*4 + j] = s;
        }
    }
    __syncthreads();
    if (tid < BM) {
        float s = red[0][tid] + red[1][tid];
        partial[((size_t)model*NT + tn)*TTOK + tm*BM + tid] = s;
    }
}

// fallback tgt (standalone)
__global__ __launch_bounds__(256) void tgt_kernel(
    const float* __restrict__ X0, const float* __restrict__ W0, const float* __restrict__ B0,
    const float* __restrict__ X1, const float* __restrict__ W1, const float* __restrict__ B1,
    const int* __restrict__ target, float* __restrict__ tgt)
{
    int gw = blockIdx.x * 4 + (threadIdx.x >> 6);
    int lane = threadIdx.x & 63;
    int model = gw >> 11;
    int t = gw & (TTOK - 1);
    const float* X = model ? X1 : X0;
    const float* W = model ? W1 : W0;
    const float* Bi = model ? B1 : B0;
    int tg = target[t];
    int stg = tg < 0 ? 0 : (tg >= VOCAB ? VOCAB - 1 : tg);
    const float* xr = X + (size_t)t * HDIM;
    const float* wrow = W + (size_t)stg * HDIM;
    float s = 0.f;
    #pragma unroll
    for (int i = 0; i < 4; ++i) {
        int k = i * 256 + lane * 4;
        f32x4 xv = *(const f32x4*)(xr + k);
        f32x4 wv = *(const f32x4*)(wrow + k);
        s += xv[0]*wv[0] + xv[1]*wv[1] + xv[2]*wv[2] + xv[3]*wv[3];
    }
    s += __shfl_xor(s, 1);  s += __shfl_xor(s, 2);  s += __shfl_xor(s, 4);
    s += __shfl_xor(s, 8);  s += __shfl_xor(s, 16); s += __shfl_xor(s, 32);
    if (lane == 0)
        tgt[model * TTOK + t] = s + Bi[stg];
}

// ---------------- parallel logZ + per-block token-logp sums ----------------
// 256 blocks; block b owns 16 consecutive g = (model,token) pairs.
// 16 threads per token (part = tid>>4) each sum tiles j = part, part+16, ...
// (reads: 16 consecutive tokens per 16-lane group = 64B coalesced).
// Output: blocksum[b] = sum of masked tok_logp over the block's 16 tokens.
__global__ __launch_bounds__(256) void logz_kernel(
    const float* __restrict__ partial, const float* __restrict__ tgt,
    const int* __restrict__ target, float* __restrict__ blocksum, int nt)
{
    const int tid = threadIdx.x;
    const int tl  = tid & 15;          // token within block
    const int part = tid >> 4;         // 0..15
    const int g = blockIdx.x * 16 + tl;
    const int m = g >> 11;
    const int t = g & (TTOK - 1);

    const float* p = partial + (size_t)m * nt * TTOK + t;
    float s = 0.f;
    for (int j = part; j < nt; j += 16)
        s += p[(size_t)j * TTOK];
    // reduce parts: wave w holds parts 4w..4w+3 (lanes: tl + 16*(part&3))
    s += __shfl_xor(s, 16);
    s += __shfl_xor(s, 32);
    __shared__ float red[4][16];
    if ((tid & 63) < 16) red[tid >> 6][tl] = s;
    __syncthreads();
    if (tid < 16) {
        float S = red[0][tid] + red[1][tid] + red[2][tid] + red[3][tid];
        int gg = blockIdx.x * 16 + tid;
        int tt = gg & (TTOK - 1);
        float lp = tgt[gg] - __logf(S);
        if (target[tt] == -100) lp = 0.f;
        // sum 16 token-logps within lanes 0..15
        lp += __shfl_xor(lp, 1); lp += __shfl_xor(lp, 2);
        lp += __shfl_xor(lp, 4); lp += __shfl_xor(lp, 8);
        if (tid == 0) blocksum[blockIdx.x] = lp;
    }
}

// ---------------- DPO loss from 256 block sums -----------------------------
// blocksum[b] belongs to seq_global = b>>4 (0..7 policy, 8..15 ref).
__global__ __launch_bounds__(256) void loss_kernel(
    const float* __restrict__ blocksum, float* __restrict__ out)
{
    int tid = threadIdx.x;
    float v = blocksum[tid];
    v += __shfl_xor(v, 1); v += __shfl_xor(v, 2);
    v += __shfl_xor(v, 4); v += __shfl_xor(v, 8);   // sum within 16-lane group
    __shared__ float ps[16];
    if ((tid & 15) == 0) ps[tid >> 4] = v;
    __syncthreads();
    if (tid == 0) {
        float loss = 0.f;
        #pragma unroll
        for (int p = 0; p < NPAIRS; ++p) {
            float cho = ps[2*p]     - ps[8 + 2*p];
            float rej = ps[2*p + 1] - ps[8 + 2*p + 1];
            float z = BETAF * (cho - rej);
            float lsig = fminf(z, 0.f) - log1pf(__expf(-fabsf(z)));
            loss += -lsig;
        }
        out[0] = loss / (float)NPAIRS;
    }
}

// fallback finalize: single block, NT=250 layout
__global__ __launch_bounds__(512) void finalize_kernel(
    const float* __restrict__ partial, const float* __restrict__ tgt,
    const int* __restrict__ target, float* __restrict__ out)
{
    int tid = threadIdx.x;
    float acc = 0.f;
    #pragma unroll
    for (int i = 0; i < 8; ++i) {
        int g = tid * 8 + i;
        int model = g >> 11;
        int t = g & (TTOK - 1);
        const float* p = partial + (size_t)model * NT * TTOK + t;
        float S = 0.f;
        for (int j = 0; j < NT; ++j) S += p[(size_t)j * TTOK];
        float lp = tgt[g] - __logf(S);
        if (target[t] == -100) lp = 0.f;
        acc += lp;
    }
    acc += __shfl_xor(acc, 1);  acc += __shfl_xor(acc, 2);
    acc += __shfl_xor(acc, 4);  acc += __shfl_xor(acc, 8);
    acc += __shfl_xor(acc, 16);
    __shared__ float ps[16];
    if ((tid & 31) == 0) ps[tid >> 5] = acc;
    __syncthreads();
    if (tid == 0) {
        float loss = 0.f;
        #pragma unroll
        for (int p = 0; p < NPAIRS; ++p) {
            float cho = ps[2*p]     - ps[8 + 2*p];
            float rej = ps[2*p + 1] - ps[8 + 2*p + 1];
            float z = BETAF * (cho - rej);
            float lsig = fminf(z, 0.f) - log1pf(__expf(-fabsf(z)));
            loss += -lsig;
        }
        out[0] = loss / (float)NPAIRS;
    }
}

extern "C" void kernel_launch(void* const* d_in, const int* in_sizes, int n_in,
                              void* d_out, int out_size, void* d_ws, size_t ws_size,
                              hipStream_t stream) {
    const float* x    = (const float*)d_in[0];
    const float* wgt  = (const float*)d_in[1];
    const float* bias = (const float*)d_in[2];
    const float* rx   = (const float*)d_in[3];
    const float* rwgt = (const float*)d_in[4];
    const float* rb   = (const float*)d_in[5];
    const int* target = (const int*)d_in[6];
    float* out = (float*)d_out;

    // ws layout
    float* partial  = (float*)d_ws;                      // 2*250*2048 f = 4 MB
    float* tgtb     = partial + (size_t)2 * NT * TTOK;   // 4096 f
    float* blocksum = tgtb + 2 * TTOK;                   // 256 f
    short* Xb       = (short*)(blocksum + 256);          // 8 MB
    short* Wb       = Xb + (size_t)2 * TTOK * HDIM;      // 131 MB
    size_t need = (size_t)((char*)(Wb + (size_t)2 * VOCAB * HDIM) - (char*)d_ws);

    if (ws_size >= need) {
        prep_kernel<<<CONV_BLOCKS, 256, 0, stream>>>(
            x, rx, wgt, rwgt, bias, rb, Xb, Wb, target, tgtb);
        gemm_expsum_bf16<<<NWG, 256, 0, stream>>>(Xb, Wb, bias, rb, partial);
        logz_kernel<<<256, 256, 0, stream>>>(partial, tgtb, target, blocksum, NT);
        loss_kernel<<<1, 256, 0, stream>>>(blocksum, out);
    } else {
        dim3 grid(MT, NT, 2);
        gemm_expsum_f32<<<grid, 256, 0, stream>>>(x, wgt, bias, rx, rwgt, rb, partial);
        tgt_kernel<<<(2 * TTOK) / 4, 256, 0, stream>>>(x, wgt, bias, rx, rwgt, rb, target, tgtb);
        finalize_kernel<<<1, 512, 0, stream>>>(partial, tgtb, target, out);
    }
}

// Round 10
// 356.217 us; speedup vs baseline: 1.2642x; 1.0151x over previous
//
#include <hip/hip_runtime.h>
#include <hip/hip_bf16.h>

#define HDIM 1024
#define VOCAB 32000
#define TTOK 2048
#define BETAF 0.1f
#define NPAIRS 4

// fallback (128-tile) geometry
#define BM 128
#define BN 128
#define BK 64
#define MT (TTOK/BM)     // 16
#define NT (VOCAB/BN)    // 250
#define KSTEPS (HDIM/BK) // 16

// main (256-tile, 8-phase) geometry
#define BM2 256
#define MT2 (TTOK/BM2)   // 8
#define NT2 (VOCAB/BM2)  // 125
#define NWG2 (MT2*NT2*2) // 2000, %8==0

#define CONV_BLOCKS 2048

typedef __attribute__((ext_vector_type(4))) float f32x4;
typedef __attribute__((ext_vector_type(8))) short bf16x8;

__device__ __forceinline__ short f2bf(float f) {
    union { float f; unsigned u; } v; v.f = f;
    return (short)((v.u + 0x7FFFu + ((v.u >> 16) & 1u)) >> 16);  // RNE
}

__device__ __forceinline__ void gld_lds16(const void* g, void* l) {
    __builtin_amdgcn_global_load_lds(
        (const __attribute__((address_space(1))) unsigned int*)g,
        (__attribute__((address_space(3))) unsigned int*)l, 16, 0, 0);
}

// ---------------- fused prep: tgt dots (waves 0-1) + fp32->bf16 convert ----
__global__ __launch_bounds__(256) void prep_kernel(
    const float* __restrict__ x,    const float* __restrict__ rx,
    const float* __restrict__ wgt,  const float* __restrict__ rwgt,
    const float* __restrict__ bias, const float* __restrict__ rb,
    short* __restrict__ Xb, short* __restrict__ Wb,
    const int* __restrict__ target, float* __restrict__ tgt)
{
    const int b = blockIdx.x;
    const int wid = threadIdx.x >> 6;
    const int lane = threadIdx.x & 63;

    if (wid < 2) {
        int gw = b * 2 + wid;                 // 0..4095 (model, token) tasks
        int model = gw >> 11;
        int t = gw & (TTOK - 1);
        const float* X  = model ? rx : x;
        const float* W  = model ? rwgt : wgt;
        const float* Bi = model ? rb : bias;
        int tg = target[t];
        int stg = tg < 0 ? 0 : (tg >= VOCAB ? VOCAB - 1 : tg);
        const float* xr = X + (size_t)t * HDIM;
        const float* wrow = W + (size_t)stg * HDIM;
        float s = 0.f;
        #pragma unroll
        for (int i = 0; i < 4; ++i) {
            int k = i * 256 + lane * 4;
            f32x4 xv = *(const f32x4*)(xr + k);
            f32x4 wv = *(const f32x4*)(wrow + k);
            s += xv[0]*wv[0] + xv[1]*wv[1] + xv[2]*wv[2] + xv[3]*wv[3];
        }
        s += __shfl_xor(s, 1);  s += __shfl_xor(s, 2);  s += __shfl_xor(s, 4);
        s += __shfl_xor(s, 8);  s += __shfl_xor(s, 16); s += __shfl_xor(s, 32);
        if (lane == 0)
            tgt[model * TTOK + t] = s + Bi[stg];
    }

    const int XN8 = TTOK * HDIM / 8;      // 262144
    const int WN8 = VOCAB * HDIM / 8;     // 4096000
    const int TOT = 2 * XN8 + 2 * WN8;    // 8716288
    const int stride = CONV_BLOCKS * 256;
    for (int i = b * 256 + threadIdx.x; i < TOT; i += stride) {
        const float* src; short* dst; int off;
        if (i < XN8)            { src = x;    dst = Xb;                          off = i; }
        else if (i < 2*XN8)     { src = rx;   dst = Xb + (size_t)TTOK*HDIM;      off = i - XN8; }
        else if (i < 2*XN8+WN8) { src = wgt;  dst = Wb;                          off = i - 2*XN8; }
        else                    { src = rwgt; dst = Wb + (size_t)VOCAB*HDIM;     off = i - 2*XN8 - WN8; }
        size_t e = (size_t)off * 8;
        f32x4 v0 = *(const f32x4*)(src + e);
        f32x4 v1 = *(const f32x4*)(src + e + 4);
        bf16x8 o;
        o[0]=f2bf(v0[0]); o[1]=f2bf(v0[1]); o[2]=f2bf(v0[2]); o[3]=f2bf(v0[3]);
        o[4]=f2bf(v1[0]); o[5]=f2bf(v1[1]); o[6]=f2bf(v1[2]); o[7]=f2bf(v1[3]);
        *(bf16x8*)(dst + e) = o;
    }
}

// ---------------- 256x256 balanced 8-phase GEMM ----------------------------
// Stage one 128-row HALF (h) of a 256x64 tile: 2 gld_lds/thread (16 KB).
// Linear LDS dest (slot c=j*512+tid at byte c*16); global source pre-swizzled
// kseg ^= row&7 so the read-side XOR involution sees a consistent layout.
__device__ __forceinline__ void stage_half(
    const short* __restrict__ gbase, int kb, int h, short* ldsTile, int tid)
{
    #pragma unroll
    for (int j = 0; j < 2; ++j) {
        int c = j * 512 + tid;            // 0..1023 chunk within half
        int r = c >> 3;                   // 0..127 row within half
        int ks = (c & 7) ^ (r & 7);       // swizzled k-segment
        gld_lds16(gbase + (size_t)(h * 128 + r) * HDIM + kb + ks * 8,
                  (char*)ldsTile + h * 16384 + (j * 8192 + ((tid >> 6) << 10)));
    }
}

// One phase: 4 af ds_reads (+8 bq reads if READB) ; stage stmt by caller
// between this and the barrier is inlined via the macro's STAGE slot.
#define PHASE(BUF_A, BUF_B, Q, READB, STAGE_STMT)                              \
    do {                                                                       \
        bf16x8 af[2][2];                                                       \
        _Pragma("unroll")                                                      \
        for (int kk = 0; kk < 2; ++kk)                                         \
            _Pragma("unroll")                                                  \
            for (int mm = 0; mm < 2; ++mm) {                                   \
                int row = arow0 + (Q)*32 + mm*16;                              \
                int byt = (row*128 + kk*64 + lhi*16) ^ ((row & 7) << 4);       \
                af[kk][mm] = *(const bf16x8*)((const char*)(BUF_A) + byt);     \
            }                                                                  \
        if (READB) {                                                           \
            _Pragma("unroll")                                                  \
            for (int kk = 0; kk < 2; ++kk)                                     \
                _Pragma("unroll")                                              \
                for (int n = 0; n < 4; ++n) {                                  \
                    int row = brow0 + n*16;                                    \
                    int byt = (row*128 + kk*64 + lhi*16) ^ ((row & 7) << 4);   \
                    bq[kk][n] = *(const bf16x8*)((const char*)(BUF_B) + byt);  \
                }                                                              \
        }                                                                      \
        STAGE_STMT;                                                            \
        __builtin_amdgcn_s_barrier();                                          \
        asm volatile("s_waitcnt lgkmcnt(0)" ::: "memory");                     \
        __builtin_amdgcn_s_setprio(1);                                         \
        _Pragma("unroll")                                                      \
        for (int kk = 0; kk < 2; ++kk)                                         \
            _Pragma("unroll")                                                  \
            for (int mm = 0; mm < 2; ++mm)                                     \
                _Pragma("unroll")                                              \
                for (int n = 0; n < 4; ++n)                                    \
                    acc[(Q)*2+mm][n] = __builtin_amdgcn_mfma_f32_16x16x32_bf16(\
                        af[kk][mm], bq[kk][n], acc[(Q)*2+mm][n], 0, 0, 0);     \
        __builtin_amdgcn_s_setprio(0);                                         \
    } while (0)

// partial layout (main path): [2][NT2][TTOK]
__global__ __launch_bounds__(512) void gemm_expsum_256(
    const short* __restrict__ Xb, const short* __restrict__ Wb,
    const float* __restrict__ B0, const float* __restrict__ B1,
    float* __restrict__ partial)
{
    __shared__ short As[2][BM2*BK];   // 64 KB
    __shared__ short Bs[2][BM2*BK];   // 64 KB
    __shared__ float red[4][BM2];     // 4 KB

    // bijective XCD swizzle (2000 % 8 == 0), tm fastest for W-panel L2 reuse
    int raw = blockIdx.x;
    int swz = (raw & 7) * (NWG2 / 8) + (raw >> 3);
    const int model = swz / (MT2 * NT2);
    int rem = swz % (MT2 * NT2);
    const int tn = rem / MT2;
    const int tm = rem % MT2;

    const short* __restrict__ X = Xb + (size_t)model * TTOK * HDIM;
    const short* __restrict__ W = Wb + (size_t)model * VOCAB * HDIM;
    const float* __restrict__ Bi = model ? B1 : B0;

    const int tid  = threadIdx.x;
    const int lane = tid & 63;
    const int w    = tid >> 6;
    const int wrM  = w >> 2, wn = w & 3;   // 2x4 wave grid; 128x64 out each
    const int l16  = lane & 15, lhi = lane >> 4;
    const int arow0 = wrM*128 + l16;
    const int brow0 = wn*64 + l16;

    const short* Ag = X + (size_t)tm * BM2 * HDIM;
    const short* Bg = W + (size_t)tn * BM2 * HDIM;

    f32x4 acc[8][4];
    #pragma unroll
    for (int m = 0; m < 8; ++m)
        #pragma unroll
        for (int n = 0; n < 4; ++n)
            acc[m][n] = (f32x4)0.f;

    // prologue: tile0 (A+B, 8 loads) + B(1) halves (4 loads); gate tile0.
    stage_half(Ag, 0, 0, As[0], tid);
    stage_half(Ag, 0, 1, As[0], tid);
    stage_half(Bg, 0, 0, Bs[0], tid);
    stage_half(Bg, 0, 1, Bs[0], tid);
    stage_half(Bg, BK, 0, Bs[1], tid);
    stage_half(Bg, BK, 1, Bs[1], tid);
    asm volatile("s_waitcnt vmcnt(4)" ::: "memory");   // tile0 landed; B(1) in flight
    __builtin_amdgcn_s_barrier();

    bf16x8 bq[2][4];

    // 8 iterations x 2 K-tiles; per-phase balanced staging (1 half = 2 loads):
    //  ph1:A0(2i+1)->buf1  ph2:A1(2i+1)  ph3:B0(2i+2)->buf0  ph4:B1(2i+2)+gate
    //  ph5:A0(2i+2)->buf0  ph6:A1(2i+2)  ph7:B0(2i+3)->buf1  ph8:B1(2i+3)+gate
    // Gates: issue-order proof => vmcnt(4) both (iter7: gate1=vmcnt(0), no gate2).
    #pragma unroll 1
    for (int i = 0; i < 8; ++i) {
        const bool st = (i < 7);
        const int kbA1 = (2*i + 1) * BK;   // tile 2i+1 (A halves -> buf1)
        const int kbN0 = (2*i + 2) * BK;   // tile 2i+2 (-> buf0)
        const int kbN1 = (2*i + 3) * BK;   // tile 2i+3 (B halves -> buf1)

        // ---- tile 2i in buf0 ----
        PHASE(As[0], Bs[0], 0, true,  { stage_half(Ag, kbA1, 0, As[1], tid); });
        __builtin_amdgcn_s_barrier();
        PHASE(As[0], Bs[0], 1, false, { stage_half(Ag, kbA1, 1, As[1], tid); });
        __builtin_amdgcn_s_barrier();
        PHASE(As[0], Bs[0], 2, false, { if (st) stage_half(Bg, kbN0, 0, Bs[0], tid); });
        __builtin_amdgcn_s_barrier();
        PHASE(As[0], Bs[0], 3, false, { if (st) stage_half(Bg, kbN0, 1, Bs[0], tid); });
        if (st) asm volatile("s_waitcnt vmcnt(4)" ::: "memory");  // A(2i+1) landed
        else    asm volatile("s_waitcnt vmcnt(0)" ::: "memory");
        __builtin_amdgcn_s_barrier();

        // ---- tile 2i+1 in buf1 ----
        PHASE(As[1], Bs[1], 0, true,  { if (st) stage_half(Ag, kbN0, 0, As[0], tid); });
        __builtin_amdgcn_s_barrier();
        PHASE(As[1], Bs[1], 1, false, { if (st) stage_half(Ag, kbN0, 1, As[0], tid); });
        __builtin_amdgcn_s_barrier();
        PHASE(As[1], Bs[1], 2, false, { if (st) stage_half(Bg, kbN1, 0, Bs[1], tid); });
        __builtin_amdgcn_s_barrier();
        PHASE(As[1], Bs[1], 3, false, { if (st) stage_half(Bg, kbN1, 1, Bs[1], tid); });
        if (st) asm volatile("s_waitcnt vmcnt(4)" ::: "memory");  // A(2i+2) landed
        __builtin_amdgcn_s_barrier();
    }

    // epilogue: per-token sum of exp(logit + bias) over this block's 256 cols
    float bv[4];
    #pragma unroll
    for (int n = 0; n < 4; ++n)
        bv[n] = Bi[tn*BM2 + wn*64 + n*16 + l16];

    #pragma unroll
    for (int m = 0; m < 8; ++m) {
        #pragma unroll
        for (int j = 0; j < 4; ++j) {
            float s = 0.f;
            #pragma unroll
            for (int n = 0; n < 4; ++n)
                s += __expf(acc[m][n][j] + bv[n]);
            s += __shfl_xor(s, 1);
            s += __shfl_xor(s, 2);
            s += __shfl_xor(s, 4);
            s += __shfl_xor(s, 8);
            if (l16 == 0)
                red[wn][wrM*128 + m*16 + lhi*4 + j] = s;
        }
    }
    __syncthreads();
    if (tid < BM2) {
        float s = red[0][tid] + red[1][tid] + red[2][tid] + red[3][tid];
        partial[((size_t)model*NT2 + tn)*TTOK + tm*BM2 + tid] = s;
    }
}

// ---------------- fallback GEMM (inline convert, explicit swizzle) ---------
__global__ __launch_bounds__(256) void gemm_expsum_f32(
    const float* __restrict__ X0, const float* __restrict__ W0, const float* __restrict__ B0,
    const float* __restrict__ X1, const float* __restrict__ W1, const float* __restrict__ B1,
    float* __restrict__ partial)
{
    const int model = blockIdx.z;
    const float* __restrict__ X = model ? X1 : X0;
    const float* __restrict__ W = model ? W1 : W0;
    const float* __restrict__ Bi = model ? B1 : B0;
    const int tm = blockIdx.x;
    const int tn = blockIdx.y;

    __shared__ short As[BM*BK];
    __shared__ short Bs[BN*BK];
    __shared__ float red[2][BM];

    const int tid  = threadIdx.x;
    const int lane = tid & 63;
    const int w    = tid >> 6;
    const int wr   = w >> 1, wc = w & 1;
    const int l16  = lane & 15, lhi = lane >> 4;

    f32x4 acc[4][4];
    #pragma unroll
    for (int m = 0; m < 4; ++m)
        #pragma unroll
        for (int n = 0; n < 4; ++n)
            acc[m][n] = (f32x4)0.f;

    for (int ks = 0; ks < KSTEPS; ++ks) {
        __syncthreads();
        const int kbase = ks * BK;
        #pragma unroll
        for (int it = 0; it < 4; ++it) {
            int s = tid + it * 256;
            int row = s >> 3, kseg = s & 7;
            const float* g = X + (size_t)(tm*BM + row)*HDIM + kbase + kseg*8;
            f32x4 v0 = *(const f32x4*)g;
            f32x4 v1 = *(const f32x4*)(g + 4);
            bf16x8 b;
            b[0]=f2bf(v0[0]); b[1]=f2bf(v0[1]); b[2]=f2bf(v0[2]); b[3]=f2bf(v0[3]);
            b[4]=f2bf(v1[0]); b[5]=f2bf(v1[1]); b[6]=f2bf(v1[2]); b[7]=f2bf(v1[3]);
            int byte = (row*128 + kseg*16) ^ ((row & 7) << 4);
            *(bf16x8*)((char*)As + byte) = b;
        }
        #pragma unroll
        for (int it = 0; it < 4; ++it) {
            int s = tid + it * 256;
            int row = s >> 3, kseg = s & 7;
            const float* g = W + (size_t)(tn*BN + row)*HDIM + kbase + kseg*8;
            f32x4 v0 = *(const f32x4*)g;
            f32x4 v1 = *(const f32x4*)(g + 4);
            bf16x8 b;
            b[0]=f2bf(v0[0]); b[1]=f2bf(v0[1]); b[2]=f2bf(v0[2]); b[3]=f2bf(v0[3]);
            b[4]=f2bf(v1[0]); b[5]=f2bf(v1[1]); b[6]=f2bf(v1[2]); b[7]=f2bf(v1[3]);
            int byte = (row*128 + kseg*16) ^ ((row & 7) << 4);
            *(bf16x8*)((char*)Bs + byte) = b;
        }
        __syncthreads();

        bf16x8 af[2][4], bfr[2][4];
        #pragma unroll
        for (int kk = 0; kk < 2; ++kk) {
            #pragma unroll
            for (int m = 0; m < 4; ++m) {
                int row = wr*64 + m*16 + l16;
                int byte = (row*128 + kk*64 + lhi*16) ^ ((row & 7) << 4);
                af[kk][m] = *(const bf16x8*)((const char*)As + byte);
            }
            #pragma unroll
            for (int n = 0; n < 4; ++n) {
                int row = wc*64 + n*16 + l16;
                int byte = (row*128 + kk*64 + lhi*16) ^ ((row & 7) << 4);
                bfr[kk][n] = *(const bf16x8*)((const char*)Bs + byte);
            }
        }
        #pragma unroll
        for (int kk = 0; kk < 2; ++kk)
            #pragma unroll
            for (int m = 0; m < 4; ++m)
                #pragma unroll
                for (int n = 0; n < 4; ++n)
                    acc[m][n] = __builtin_amdgcn_mfma_f32_16x16x32_bf16(
                        af[kk][m], bfr[kk][n], acc[m][n], 0, 0, 0);
    }

    float bv[4];
    #pragma unroll
    for (int n = 0; n < 4; ++n)
        bv[n] = Bi[tn*BN + wc*64 + n*16 + l16];

    #pragma unroll
    for (int m = 0; m < 4; ++m) {
        #pragma unroll
        for (int j = 0; j < 4; ++j) {
            float s = 0.f;
            #pragma unroll
            for (int n = 0; n < 4; ++n)
                s += __expf(acc[m][n][j] + bv[n]);
            s += __shfl_xor(s, 1);
            s += __shfl_xor(s, 2);
            s += __shfl_xor(s, 4);
            s += __shfl_xor(s, 8);
            if (l16 == 0)
                red[wc][wr*64 + m*16 + lhi*4 + j] = s;
        }
    }
    __syncthreads();
    if (tid < BM) {
        float s = red[0][tid] + red[1][tid];
        partial[((size_t)model*NT + tn)*TTOK + tm*BM + tid] = s;
    }
}

// fallback tgt (standalone)
__global__ __launch_bounds__(256) void tgt_kernel(
    const float* __restrict__ X0, const float* __restrict__ W0, const float* __restrict__ B0,
    const float* __restrict__ X1, const float* __restrict__ W1, const float* __restrict__ B1,
    const int* __restrict__ target, float* __restrict__ tgt)
{
    int gw = blockIdx.x * 4 + (threadIdx.x >> 6);
    int lane = threadIdx.x & 63;
    int model = gw >> 11;
    int t = gw & (TTOK - 1);
    const float* X = model ? X1 : X0;
    const float* W = model ? W1 : W0;
    const float* Bi = model ? B1 : B0;
    int tg = target[t];
    int stg = tg < 0 ? 0 : (tg >= VOCAB ? VOCAB - 1 : tg);
    const float* xr = X + (size_t)t * HDIM;
    const float* wrow = W + (size_t)stg * HDIM;
    float s = 0.f;
    #pragma unroll
    for (int i = 0; i < 4; ++i) {
        int k = i * 256 + lane * 4;
        f32x4 xv = *(const f32x4*)(xr + k);
        f32x4 wv = *(const f32x4*)(wrow + k);
        s += xv[0]*wv[0] + xv[1]*wv[1] + xv[2]*wv[2] + xv[3]*wv[3];
    }
    s += __shfl_xor(s, 1);  s += __shfl_xor(s, 2);  s += __shfl_xor(s, 4);
    s += __shfl_xor(s, 8);  s += __shfl_xor(s, 16); s += __shfl_xor(s, 32);
    if (lane == 0)
        tgt[model * TTOK + t] = s + Bi[stg];
}

// ---------------- parallel logZ + per-block token-logp sums ----------------
__global__ __launch_bounds__(256) void logz_kernel(
    const float* __restrict__ partial, const float* __restrict__ tgt,
    const int* __restrict__ target, float* __restrict__ blocksum, int nt)
{
    const int tid = threadIdx.x;
    const int tl  = tid & 15;          // token within block
    const int part = tid >> 4;         // 0..15
    const int g = blockIdx.x * 16 + tl;
    const int m = g >> 11;
    const int t = g & (TTOK - 1);

    const float* p = partial + (size_t)m * nt * TTOK + t;
    float s = 0.f;
    for (int j = part; j < nt; j += 16)
        s += p[(size_t)j * TTOK];
    s += __shfl_xor(s, 16);
    s += __shfl_xor(s, 32);
    __shared__ float red[4][16];
    if ((tid & 63) < 16) red[tid >> 6][tl] = s;
    __syncthreads();
    if (tid < 16) {
        float S = red[0][tid] + red[1][tid] + red[2][tid] + red[3][tid];
        int gg = blockIdx.x * 16 + tid;
        int tt = gg & (TTOK - 1);
        float lp = tgt[gg] - __logf(S);
        if (target[tt] == -100) lp = 0.f;
        lp += __shfl_xor(lp, 1); lp += __shfl_xor(lp, 2);
        lp += __shfl_xor(lp, 4); lp += __shfl_xor(lp, 8);
        if (tid == 0) blocksum[blockIdx.x] = lp;
    }
}

// ---------------- DPO loss from 256 block sums -----------------------------
__global__ __launch_bounds__(256) void loss_kernel(
    const float* __restrict__ blocksum, float* __restrict__ out)
{
    int tid = threadIdx.x;
    float v = blocksum[tid];
    v += __shfl_xor(v, 1); v += __shfl_xor(v, 2);
    v += __shfl_xor(v, 4); v += __shfl_xor(v, 8);
    __shared__ float ps[16];
    if ((tid & 15) == 0) ps[tid >> 4] = v;
    __syncthreads();
    if (tid == 0) {
        float loss = 0.f;
        #pragma unroll
        for (int p = 0; p < NPAIRS; ++p) {
            float cho = ps[2*p]     - ps[8 + 2*p];
            float rej = ps[2*p + 1] - ps[8 + 2*p + 1];
            float z = BETAF * (cho - rej);
            float lsig = fminf(z, 0.f) - log1pf(__expf(-fabsf(z)));
            loss += -lsig;
        }
        out[0] = loss / (float)NPAIRS;
    }
}

// fallback finalize: single block, NT=250 layout
__global__ __launch_bounds__(512) void finalize_kernel(
    const float* __restrict__ partial, const float* __restrict__ tgt,
    const int* __restrict__ target, float* __restrict__ out)
{
    int tid = threadIdx.x;
    float acc = 0.f;
    #pragma unroll
    for (int i = 0; i < 8; ++i) {
        int g = tid * 8 + i;
        int model = g >> 11;
        int t = g & (TTOK - 1);
        const float* p = partial + (size_t)model * NT * TTOK + t;
        float S = 0.f;
        for (int j = 0; j < NT; ++j) S += p[(size_t)j * TTOK];
        float lp = tgt[g] - __logf(S);
        if (target[t] == -100) lp = 0.f;
        acc += lp;
    }
    acc += __shfl_xor(acc, 1);  acc += __shfl_xor(acc, 2);
    acc += __shfl_xor(acc, 4);  acc += __shfl_xor(acc, 8);
    acc += __shfl_xor(acc, 16);
    __shared__ float ps[16];
    if ((tid & 31) == 0) ps[tid >> 5] = acc;
    __syncthreads();
    if (tid == 0) {
        float loss = 0.f;
        #pragma unroll
        for (int p = 0; p < NPAIRS; ++p) {
            float cho = ps[2*p]     - ps[8 + 2*p];
            float rej = ps[2*p + 1] - ps[8 + 2*p + 1];
            float z = BETAF * (cho - rej);
            float lsig = fminf(z, 0.f) - log1pf(__expf(-fabsf(z)));
            loss += -lsig;
        }
        out[0] = loss / (float)NPAIRS;
    }
}

extern "C" void kernel_launch(void* const* d_in, const int* in_sizes, int n_in,
                              void* d_out, int out_size, void* d_ws, size_t ws_size,
                              hipStream_t stream) {
    const float* x    = (const float*)d_in[0];
    const float* wgt  = (const float*)d_in[1];
    const float* bias = (const float*)d_in[2];
    const float* rx   = (const float*)d_in[3];
    const float* rwgt = (const float*)d_in[4];
    const float* rb   = (const float*)d_in[5];
    const int* target = (const int*)d_in[6];
    float* out = (float*)d_out;

    // ws layout (partial region sized for the larger NT=250 fallback layout)
    float* partial  = (float*)d_ws;                      // 4 MB
    float* tgtb     = partial + (size_t)2 * NT * TTOK;   // 4096 f
    float* blocksum = tgtb + 2 * TTOK;                   // 256 f
    short* Xb       = (short*)(blocksum + 256);          // 8 MB
    short* Wb       = Xb + (size_t)2 * TTOK * HDIM;      // 131 MB
    size_t need = (size_t)((char*)(Wb + (size_t)2 * VOCAB * HDIM) - (char*)d_ws);

    if (ws_size >= need) {
        prep_kernel<<<CONV_BLOCKS, 256, 0, stream>>>(
            x, rx, wgt, rwgt, bias, rb, Xb, Wb, target, tgtb);
        gemm_expsum_256<<<NWG2, 512, 0, stream>>>(Xb, Wb, bias, rb, partial);
        logz_kernel<<<256, 256, 0, stream>>>(partial, tgtb, target, blocksum, NT2);
        loss_kernel<<<1, 256, 0, stream>>>(blocksum, out);
    } else {
        dim3 grid(MT, NT, 2);
        gemm_expsum_f32<<<grid, 256, 0, stream>>>(x, wgt, bias, rx, rwgt, rb, partial);
        tgt_kernel<<<(2 * TTOK) / 4, 256, 0, stream>>>(x, wgt, bias, rx, rwgt, rb, target, tgtb);
        finalize_kernel<<<1, 512, 0, stream>>>(partial, tgtb, target, out);
    }
}